// Round 4
// baseline (410.967 us; speedup 1.0000x reference)
//
#include <hip/hip_runtime.h>
#include <hip/hip_bf16.h>

#define HH 96
#define WW 96
#define NPIX 9216          // H*W
#define DDIM 1152          // 128*9
#define NKT 36             // K tiles of 32
#define BM 256
#define BN 256
#define MT 36              // NPIX/BM
#define NT 36              // NPIX/BN
#define NBLK (MT * NT)     // 1296, %8 == 0
#define TOTAL_ELEMS 1179648
#define CG 32              // channels per build group

typedef float f32x4 __attribute__((ext_vector_type(4)));
typedef __bf16 bf16x8 __attribute__((ext_vector_type(8)));

__device__ __forceinline__ void gload_lds16(const void* g, void* l) {
  __builtin_amdgcn_global_load_lds((const __attribute__((address_space(1))) void*)g,
                                   (__attribute__((address_space(3))) void*)l, 16, 0, 0);
}

// Patch builder: block = (row y, channel-group cg, src). LDS-staged coalesced reads,
// 16B vector writes of P rows; also emits style_T [pix][c] f32 when requested.
__global__ __launch_bounds__(256)
void build_patches_kernel(const float* __restrict__ style_f,
                          const float* __restrict__ content_f,
                          __bf16* __restrict__ Ps, __bf16* __restrict__ Pc,
                          float* __restrict__ styT) {
  __shared__ float ftile[CG][3][104];
  const int y = blockIdx.x;            // 0..95
  const int cg = blockIdx.y;           // 0..3
  const bool is_style = (blockIdx.z == 0);
  const float* f = is_style ? style_f : content_f;
  __bf16* P = is_style ? Ps : Pc;
  const int tid = threadIdx.x;

  for (int i = tid; i < CG * 3 * 96; i += 256) {
    int cl = i / 288, rem = i - cl * 288;
    int yy = rem / 96, xx = rem - yy * 96;
    int gy = y + yy - 1;
    float v = (gy >= 0 && gy < HH) ? f[(size_t)(cg * CG + cl) * NPIX + gy * WW + xx] : 0.f;
    ftile[cl][yy][xx] = v;
  }
  __syncthreads();

  if (is_style && styT != nullptr) {
    for (int i = tid; i < 96 * CG; i += 256) {
      int px = i / CG, cl = i - px * CG;
      styT[(size_t)(y * WW + px) * 128 + cg * CG + cl] = ftile[cl][1][px];
    }
  }

  for (int j = tid; j < 96 * 36; j += 256) {
    int px = j / 36, wi = j - px * 36;
    bf16x8 tmp;
#pragma unroll
    for (int u = 0; u < 8; ++u) {
      int e = wi * 8 + u;
      int cl = e / 9, t = e - cl * 9;
      int ki = t / 3, kj = t - ki * 3;
      int xx = px + kj - 1;
      float v = (xx >= 0 && xx < WW) ? ftile[cl][ki][xx] : 0.f;
      tmp[u] = (__bf16)v;
    }
    *(bf16x8*)(P + (size_t)(y * WW + px) * DDIM + cg * 288 + wi * 8) = tmp;
  }
}

// Deterministic per-pixel style norms from Ps rows (one wave per pixel).
__global__ __launch_bounds__(256)
void norm_kernel(const __bf16* __restrict__ Ps, float* __restrict__ rnorm) {
  const int n = blockIdx.x * 4 + (threadIdx.x >> 6);
  const int lane = threadIdx.x & 63;
  const bf16x8* row = (const bf16x8*)(Ps + (size_t)n * DDIM);
  float ss = 0.f;
#pragma unroll
  for (int i = 0; i < 3; ++i) {
    int idx = i * 64 + lane;
    if (idx < 144) {
      bf16x8 v = row[idx];
#pragma unroll
      for (int u = 0; u < 8; ++u) { float x = (float)v[u]; ss += x * x; }
    }
  }
#pragma unroll
  for (int m = 1; m < 64; m <<= 1) ss += __shfl_xor(ss, m, 64);
  if (lane == 0) rnorm[n] = 1.0f / fmaxf(sqrtf(ss), 1e-12f);
}

// Fused GEMM + argmax, 8-phase-style schedule:
// 256x256 tile, 512 thr / 8 waves (2M x 4N), wave tile 128x64, BK=32,
// QUAD-buffered LDS (4 x 32KB), stage depth 3, counted vmcnt(8) once per tile,
// 2 compute phases per tile (16 MFMA each) with raw barriers + sched_barrier + setprio.
__global__ __launch_bounds__(512, 2)
void gemm_argmax_kernel(const __bf16* __restrict__ Pc,
                        const __bf16* __restrict__ Ps,
                        const float* __restrict__ rnorm,
                        unsigned long long* __restrict__ keytab) {
  __shared__ int4 smem4[8192];  // 128 KB: 4 bufs x (A 16KB + B 16KB)
  char* smem = (char*)smem4;
  const int tid = threadIdx.x;
  const int lane = tid & 63;
  const int wid = tid >> 6;
  const int l15 = lane & 15;
  const int lg = lane >> 4;
  const int wm = wid >> 2;     // 0..1
  const int wn = wid & 3;      // 0..3

  const int orig = blockIdx.x;
  const int swz = (orig & 7) * (NBLK / 8) + (orig >> 3);  // bijective (1296%8==0)
  const int mt = swz / NT;
  const int nt = swz - mt * NT;
  const int bm0 = mt * BM;
  const int sbase = nt * BN;

  // staging: row = tid/4 (+128 per 2nd gload), phys slot = tid&3,
  // logical k-slot = slot ^ ((row>>1)&3) = (tid&3) ^ ((tid>>3)&3)
  const int srow = tid >> 2;
  const int sg = (tid & 3) ^ ((tid >> 3) & 3);
  const __bf16* pa = Pc + (size_t)(bm0 + srow) * DDIM + sg * 8;
  const __bf16* pb = Ps + (size_t)(sbase + srow) * DDIM + sg * 8;
  const int sdst = tid * 16;

  auto stage = [&](int buf, int kt) {
    char* base = smem + buf * 32768 + sdst;
    const int ko = kt * 32;
    gload_lds16(pa + ko, base);
    gload_lds16(pa + (size_t)128 * DDIM + ko, base + 8192);
    gload_lds16(pb + ko, base + 16384);
    gload_lds16(pb + (size_t)128 * DDIM + ko, base + 24576);
  };

  // fragment read offsets: row r, phys slot = lg ^ ((r>>1)&3); (r>>1)&3 == (l15>>1)&3
  const int sx = (lg ^ ((l15 >> 1) & 3)) << 4;
  int aoff[8], boff[4];
#pragma unroll
  for (int mf = 0; mf < 8; ++mf)
    aoff[mf] = (wm * 128 + mf * 16 + l15) * 64 + sx;
#pragma unroll
  for (int nf = 0; nf < 4; ++nf)
    boff[nf] = 16384 + (wn * 64 + nf * 16 + l15) * 64 + sx;

  f32x4 acc[8][4];
#pragma unroll
  for (int mf = 0; mf < 8; ++mf)
#pragma unroll
    for (int nf = 0; nf < 4; ++nf) {
      f32x4 z = {0.f, 0.f, 0.f, 0.f};
      acc[mf][nf] = z;
    }

  // prologue: stage tiles 0,1,2 (12 gloads); drain tile 0 (leave 8)
  stage(0, 0);
  stage(1, 1);
  stage(2, 2);
  asm volatile("s_waitcnt vmcnt(8)" ::: "memory");
  __builtin_amdgcn_s_barrier();
  __builtin_amdgcn_sched_barrier(0);

  for (int T = 0; T < NKT; ++T) {
    const char* bp = smem + (T & 3) * 32768;
    // ---- phase A: read A frags + B[0..1], prefetch tile T+3, MFMA nf=0,1 ----
    bf16x8 af[8], b01[2];
#pragma unroll
    for (int mf = 0; mf < 8; ++mf)
      af[mf] = __builtin_bit_cast(bf16x8, *(const int4*)(bp + aoff[mf]));
    b01[0] = __builtin_bit_cast(bf16x8, *(const int4*)(bp + boff[0]));
    b01[1] = __builtin_bit_cast(bf16x8, *(const int4*)(bp + boff[1]));
    if (T < NKT - 3) stage((T + 3) & 3, T + 3);
    __builtin_amdgcn_s_barrier();
    __builtin_amdgcn_sched_barrier(0);
    __builtin_amdgcn_s_setprio(1);
#pragma unroll
    for (int mf = 0; mf < 8; ++mf) {
      acc[mf][0] = __builtin_amdgcn_mfma_f32_16x16x32_bf16(af[mf], b01[0], acc[mf][0], 0, 0, 0);
      acc[mf][1] = __builtin_amdgcn_mfma_f32_16x16x32_bf16(af[mf], b01[1], acc[mf][1], 0, 0, 0);
    }
    __builtin_amdgcn_s_setprio(0);
    __builtin_amdgcn_s_barrier();
    __builtin_amdgcn_sched_barrier(0);
    // ---- phase B: read B[2..3], counted vmcnt (drain tile T+1), MFMA nf=2,3 ----
    bf16x8 b23[2];
    b23[0] = __builtin_bit_cast(bf16x8, *(const int4*)(bp + boff[2]));
    b23[1] = __builtin_bit_cast(bf16x8, *(const int4*)(bp + boff[3]));
    if (T < NKT - 3) {
      asm volatile("s_waitcnt vmcnt(8)" ::: "memory");   // leave tiles T+2,T+3 in flight
    } else if (T == NKT - 3) {
      asm volatile("s_waitcnt vmcnt(4)" ::: "memory");   // leave tile T+2(=35)
    } else {
      asm volatile("s_waitcnt vmcnt(0)" ::: "memory");
    }
    __builtin_amdgcn_s_barrier();
    __builtin_amdgcn_sched_barrier(0);
    __builtin_amdgcn_s_setprio(1);
#pragma unroll
    for (int mf = 0; mf < 8; ++mf) {
      acc[mf][2] = __builtin_amdgcn_mfma_f32_16x16x32_bf16(af[mf], b23[0], acc[mf][2], 0, 0, 0);
      acc[mf][3] = __builtin_amdgcn_mfma_f32_16x16x32_bf16(af[mf], b23[1], acc[mf][3], 0, 0, 0);
    }
    __builtin_amdgcn_s_setprio(0);
    __builtin_amdgcn_s_barrier();
    __builtin_amdgcn_sched_barrier(0);
  }

  // Epilogue: per-row argmax over this block's 256 cols -> 64-bit monotone-key atomicMax
  float rn[4];
#pragma unroll
  for (int nf = 0; nf < 4; ++nf) rn[nf] = rnorm[sbase + wn * 64 + nf * 16 + l15];
#pragma unroll
  for (int mf = 0; mf < 8; ++mf)
#pragma unroll
    for (int r = 0; r < 4; ++r) {
      float v = -3.0e38f;
      int bi = 0;
#pragma unroll
      for (int nf = 0; nf < 4; ++nf) {           // ascending cols: strict > keeps first max
        float x = acc[mf][nf][r] * rn[nf];
        int col = sbase + wn * 64 + nf * 16 + l15;
        if (x > v) { v = x; bi = col; }
      }
#pragma unroll
      for (int m = 1; m < 16; m <<= 1) {
        float ov = __shfl_xor(v, m, 64);
        int oi = __shfl_xor(bi, m, 64);
        if (ov > v || (ov == v && oi < bi)) { v = ov; bi = oi; }
      }
      if (l15 == 0) {
        int row = bm0 + wm * 128 + mf * 16 + lg * 4 + r;
        unsigned u = __float_as_uint(v);
        u ^= (unsigned)((int)u >> 31) | 0x80000000u;
        unsigned long long key =
            ((unsigned long long)u << 32) | (unsigned)(0xFFFFFFFFu ^ (unsigned)bi);
        atomicMax(keytab + row, key);
      }
    }
}

// Recon+MSE: block = 2 pixels x 128 channels.
template <bool TMODE>
__global__ __launch_bounds__(256)
void recon_mse_kernel(const __bf16* __restrict__ Pc, const __bf16* __restrict__ Ps,
                      const float* __restrict__ styT,
                      const unsigned long long* __restrict__ keytab,
                      float* __restrict__ out) {
  const int pix = blockIdx.x * 2 + (threadIdx.x >> 7);
  const int c = threadIdx.x & 127;
  const int y = pix / WW, x = pix - (pix / WW) * WW;
  float sum = 0.f, cnt = 0.f;
#pragma unroll
  for (int ki = 0; ki < 3; ++ki) {
    int yn = y - ki + 1;
    if (yn < 0 || yn >= HH) continue;
#pragma unroll
    for (int kj = 0; kj < 3; ++kj) {
      int xn = x - kj + 1;
      if (xn < 0 || xn >= WW) continue;
      cnt += 1.f;
      int m = (int)(0xFFFFFFFFu ^ (unsigned)(keytab[yn * WW + xn] & 0xFFFFFFFFull));
      if (TMODE) {
        int ys = m / WW, xs = m - (m / WW) * WW;
        int sy = ys + ki - 1, sx = xs + kj - 1;
        if (sy >= 0 && sy < HH && sx >= 0 && sx < WW)
          sum += styT[(size_t)(sy * WW + sx) * 128 + c];
      } else {
        sum += (float)Ps[(size_t)m * DDIM + c * 9 + ki * 3 + kj];
      }
    }
  }
  float recon = sum / (cnt + 1e-8f);
  float cv = (float)Pc[(size_t)pix * DDIM + c * 9 + 4];
  float d = cv - recon;
  float sq = d * d;
#pragma unroll
  for (int m = 32; m > 0; m >>= 1) sq += __shfl_down(sq, m, 64);
  __shared__ float wsum[4];
  int lane = threadIdx.x & 63, w = threadIdx.x >> 6;
  if (lane == 0) wsum[w] = sq;
  __syncthreads();
  if (threadIdx.x == 0)
    atomicAdd(out, (wsum[0] + wsum[1] + wsum[2] + wsum[3]) * (1.0f / (float)TOTAL_ELEMS));
}

extern "C" void kernel_launch(void* const* d_in, const int* in_sizes, int n_in,
                              void* d_out, int out_size, void* d_ws, size_t ws_size,
                              hipStream_t stream) {
  const float* content = (const float*)d_in[0];
  const float* stylef = (const float*)d_in[1];
  float* out = (float*)d_out;
  char* ws = (char*)d_ws;

  const size_t PS_OFF = 0;
  const size_t PC_OFF = (size_t)NPIX * DDIM * 2;       // 21,233,664
  const size_t RN_OFF = PC_OFF * 2;                    // 42,467,328
  const size_t KEY_OFF = RN_OFF + (size_t)NPIX * 4;    // 42,504,192
  const size_t ST_OFF = KEY_OFF + (size_t)NPIX * 8;    // 42,577,920
  const size_t END_T = ST_OFF + (size_t)NPIX * 128 * 4;

  __bf16* Ps = (__bf16*)(ws + PS_OFF);
  __bf16* Pc = (__bf16*)(ws + PC_OFF);
  float* rnorm = (float*)(ws + RN_OFF);
  unsigned long long* keytab = (unsigned long long*)(ws + KEY_OFF);
  const bool tmode = ws_size >= END_T;
  float* styT = tmode ? (float*)(ws + ST_OFF) : nullptr;

  hipMemsetAsync(d_out, 0, (size_t)out_size * sizeof(float), stream);
  hipMemsetAsync(keytab, 0, (size_t)NPIX * 8, stream);
  build_patches_kernel<<<dim3(96, 4, 2), 256, 0, stream>>>(stylef, content, Ps, Pc, styT);
  norm_kernel<<<NPIX / 4, 256, 0, stream>>>(Ps, rnorm);
  gemm_argmax_kernel<<<NBLK, 512, 0, stream>>>(Pc, Ps, rnorm, keytab);
  if (tmode)
    recon_mse_kernel<true><<<NPIX / 2, 256, 0, stream>>>(Pc, Ps, styT, keytab, out);
  else
    recon_mse_kernel<false><<<NPIX / 2, 256, 0, stream>>>(Pc, Ps, nullptr, keytab, out);
}

// Round 5
// 383.582 us; speedup vs baseline: 1.0714x; 1.0714x over previous
//
#include <hip/hip_runtime.h>
#include <hip/hip_bf16.h>

#define HH 96
#define WW 96
#define NPIX 9216          // H*W
#define DDIM 1152          // 128*9
#define NKT 36             // K tiles of 32
#define BM 128
#define BN 128
#define MT 72              // NPIX/BM
#define NT 72              // NPIX/BN
#define NBLK (MT * NT)     // 5184, %8 == 0
#define TOTAL_ELEMS 1179648
#define CG 32              // channels per build group

typedef float f32x4 __attribute__((ext_vector_type(4)));
typedef __bf16 bf16x8 __attribute__((ext_vector_type(8)));

__device__ __forceinline__ void gload_lds16(const void* g, void* l) {
  __builtin_amdgcn_global_load_lds((const __attribute__((address_space(1))) void*)g,
                                   (__attribute__((address_space(3))) void*)l, 16, 0, 0);
}

// Patch builder: block = (row y, channel-group cg, src). LDS-staged coalesced reads,
// 16B vector writes of P rows; also emits style_T [pix][c] f32 when requested.
__global__ __launch_bounds__(256)
void build_patches_kernel(const float* __restrict__ style_f,
                          const float* __restrict__ content_f,
                          __bf16* __restrict__ Ps, __bf16* __restrict__ Pc,
                          float* __restrict__ styT) {
  __shared__ float ftile[CG][3][104];
  const int y = blockIdx.x;            // 0..95
  const int cg = blockIdx.y;           // 0..3
  const bool is_style = (blockIdx.z == 0);
  const float* f = is_style ? style_f : content_f;
  __bf16* P = is_style ? Ps : Pc;
  const int tid = threadIdx.x;

  for (int i = tid; i < CG * 3 * 96; i += 256) {
    int cl = i / 288, rem = i - cl * 288;
    int yy = rem / 96, xx = rem - yy * 96;
    int gy = y + yy - 1;
    float v = (gy >= 0 && gy < HH) ? f[(size_t)(cg * CG + cl) * NPIX + gy * WW + xx] : 0.f;
    ftile[cl][yy][xx] = v;
  }
  __syncthreads();

  if (is_style && styT != nullptr) {
    for (int i = tid; i < 96 * CG; i += 256) {
      int px = i / CG, cl = i - px * CG;
      styT[(size_t)(y * WW + px) * 128 + cg * CG + cl] = ftile[cl][1][px];
    }
  }

  for (int j = tid; j < 96 * 36; j += 256) {
    int px = j / 36, wi = j - px * 36;
    bf16x8 tmp;
#pragma unroll
    for (int u = 0; u < 8; ++u) {
      int e = wi * 8 + u;
      int cl = e / 9, t = e - cl * 9;
      int ki = t / 3, kj = t - ki * 3;
      int xx = px + kj - 1;
      float v = (xx >= 0 && xx < WW) ? ftile[cl][ki][xx] : 0.f;
      tmp[u] = (__bf16)v;
    }
    *(bf16x8*)(P + (size_t)(y * WW + px) * DDIM + cg * 288 + wi * 8) = tmp;
  }
}

// Deterministic per-pixel style norms from Ps rows (one wave per pixel).
__global__ __launch_bounds__(256)
void norm_kernel(const __bf16* __restrict__ Ps, float* __restrict__ rnorm) {
  const int n = blockIdx.x * 4 + (threadIdx.x >> 6);
  const int lane = threadIdx.x & 63;
  const bf16x8* row = (const bf16x8*)(Ps + (size_t)n * DDIM);
  float ss = 0.f;
#pragma unroll
  for (int i = 0; i < 3; ++i) {
    int idx = i * 64 + lane;
    if (idx < 144) {
      bf16x8 v = row[idx];
#pragma unroll
      for (int u = 0; u < 8; ++u) { float x = (float)v[u]; ss += x * x; }
    }
  }
#pragma unroll
  for (int m = 1; m < 64; m <<= 1) ss += __shfl_xor(ss, m, 64);
  if (lane == 0) rnorm[n] = 1.0f / fmaxf(sqrtf(ss), 1e-12f);
}

// Fused GEMM + argmax, catalog "minimum 2-phase" structure:
// 128x128 tile, 256 thr / 4 waves (2M x 2N), wave tile 64x64 (4x4 frags of 16x16x32).
// TRIPLE-buffered LDS (3 x 16KB = 48KB -> 3 blocks/CU), stage depth 2,
// ONE s_barrier per K-tile, counted vmcnt(4) (never 0 until epilogue),
// STAGE issued before ds_read+MFMA, setprio around MFMA cluster.
__global__ __launch_bounds__(256, 3)
void gemm_argmax_kernel(const __bf16* __restrict__ Pc,
                        const __bf16* __restrict__ Ps,
                        const float* __restrict__ rnorm,
                        unsigned long long* __restrict__ keytab) {
  __shared__ int4 smem4[3072];  // 48 KB: 3 bufs x (A 8KB + B 8KB)
  char* smem = (char*)smem4;
  const int tid = threadIdx.x;
  const int lane = tid & 63;
  const int wid = tid >> 6;
  const int l15 = lane & 15;
  const int lg = lane >> 4;
  const int wm = wid >> 1;     // 0..1 (M half)
  const int wn = wid & 1;      // 0..1 (N half)

  const int orig = blockIdx.x;
  const int swz = (orig & 7) * (NBLK / 8) + (orig >> 3);  // bijective (5184%8==0)
  const int mt = swz / NT;     // A-panel-major runs within an XCD
  const int nt = swz - mt * NT;
  const int bm0 = mt * BM;
  const int sbase = nt * BN;

  // staging: row = i*64 + tid/4, phys slot = tid&3,
  // logical k-slot = (tid&3) ^ ((row>>1)&3) = (tid&3) ^ ((tid>>3)&3)
  const int srow = tid >> 2;
  const int sg = (tid & 3) ^ ((tid >> 3) & 3);
  const __bf16* pa = Pc + (size_t)(bm0 + srow) * DDIM + sg * 8;
  const __bf16* pb = Ps + (size_t)(sbase + srow) * DDIM + sg * 8;
  const int sdst = tid * 16;

  auto stage = [&](int buf, int kt) {  // 4 gloads: A 2x4KB, B 2x4KB
    char* base = smem + buf * 16384 + sdst;
    const int ko = kt * 32;
    gload_lds16(pa + ko, base);
    gload_lds16(pa + (size_t)64 * DDIM + ko, base + 4096);
    gload_lds16(pb + ko, base + 8192);
    gload_lds16(pb + (size_t)64 * DDIM + ko, base + 12288);
  };

  // fragment read offsets: row r, phys slot = lg ^ ((r>>1)&3); (r>>1)&3 == (l15>>1)&3
  const int sx = (lg ^ ((l15 >> 1) & 3)) << 4;
  int aoff[4], boff[4];
#pragma unroll
  for (int mf = 0; mf < 4; ++mf)
    aoff[mf] = (wm * 64 + mf * 16 + l15) * 64 + sx;
#pragma unroll
  for (int nf = 0; nf < 4; ++nf)
    boff[nf] = 8192 + (wn * 64 + nf * 16 + l15) * 64 + sx;

  f32x4 acc[4][4];
#pragma unroll
  for (int mf = 0; mf < 4; ++mf)
#pragma unroll
    for (int nf = 0; nf < 4; ++nf) {
      f32x4 z = {0.f, 0.f, 0.f, 0.f};
      acc[mf][nf] = z;
    }

  // prologue: stage tiles 0,1 (8 loads); drain tile 0 (leave tile 1's 4)
  stage(0, 0);
  stage(1, 1);
  asm volatile("s_waitcnt vmcnt(4)" ::: "memory");
  __builtin_amdgcn_s_barrier();
  __builtin_amdgcn_sched_barrier(0);

  int sb = 2, cb = 0;
  for (int t = 0; t < NKT; ++t) {
    if (t < NKT - 2) {
      stage(sb, t + 2);                 // issue 4 loads (depth-2 ahead)
      sb = (sb == 2) ? 0 : sb + 1;
    }
    const char* bp = smem + cb * 16384;
    bf16x8 af[4], bv[4];
#pragma unroll
    for (int mf = 0; mf < 4; ++mf)
      af[mf] = __builtin_bit_cast(bf16x8, *(const int4*)(bp + aoff[mf]));
#pragma unroll
    for (int nf = 0; nf < 4; ++nf)
      bv[nf] = __builtin_bit_cast(bf16x8, *(const int4*)(bp + boff[nf]));
    __builtin_amdgcn_s_setprio(1);
#pragma unroll
    for (int mf = 0; mf < 4; ++mf)
#pragma unroll
      for (int nf = 0; nf < 4; ++nf)
        acc[mf][nf] = __builtin_amdgcn_mfma_f32_16x16x32_bf16(af[mf], bv[nf], acc[mf][nf], 0, 0, 0);
    __builtin_amdgcn_s_setprio(0);
    // drain tile t+1 (the 4 older of the <=8 outstanding); leave t+2's in flight
    if (t < NKT - 2) {
      asm volatile("s_waitcnt vmcnt(4)" ::: "memory");
    } else if (t == NKT - 2) {
      asm volatile("s_waitcnt vmcnt(0)" ::: "memory");
    }
    if (t < NKT - 1) {
      __builtin_amdgcn_s_barrier();     // single barrier per K-tile
      __builtin_amdgcn_sched_barrier(0);
    }
    cb = (cb == 2) ? 0 : cb + 1;
  }

  // Epilogue: per-row argmax over this block's 128 cols -> 64-bit monotone-key atomicMax
  float rn[4];
#pragma unroll
  for (int nf = 0; nf < 4; ++nf) rn[nf] = rnorm[sbase + wn * 64 + nf * 16 + l15];
#pragma unroll
  for (int mf = 0; mf < 4; ++mf)
#pragma unroll
    for (int r = 0; r < 4; ++r) {
      float v = -3.0e38f;
      int bi = 0;
#pragma unroll
      for (int nf = 0; nf < 4; ++nf) {           // ascending cols: strict > keeps first max
        float x = acc[mf][nf][r] * rn[nf];
        int col = sbase + wn * 64 + nf * 16 + l15;
        if (x > v) { v = x; bi = col; }
      }
#pragma unroll
      for (int m = 1; m < 16; m <<= 1) {
        float ov = __shfl_xor(v, m, 64);
        int oi = __shfl_xor(bi, m, 64);
        if (ov > v || (ov == v && oi < bi)) { v = ov; bi = oi; }
      }
      if (l15 == 0) {
        int row = bm0 + wm * 64 + mf * 16 + lg * 4 + r;
        unsigned u = __float_as_uint(v);
        u ^= (unsigned)((int)u >> 31) | 0x80000000u;
        unsigned long long key =
            ((unsigned long long)u << 32) | (unsigned)(0xFFFFFFFFu ^ (unsigned)bi);
        atomicMax(keytab + row, key);
      }
    }
}

// Recon+MSE: block = 2 pixels x 128 channels.
template <bool TMODE>
__global__ __launch_bounds__(256)
void recon_mse_kernel(const __bf16* __restrict__ Pc, const __bf16* __restrict__ Ps,
                      const float* __restrict__ styT,
                      const unsigned long long* __restrict__ keytab,
                      float* __restrict__ out) {
  const int pix = blockIdx.x * 2 + (threadIdx.x >> 7);
  const int c = threadIdx.x & 127;
  const int y = pix / WW, x = pix - (pix / WW) * WW;
  float sum = 0.f, cnt = 0.f;
#pragma unroll
  for (int ki = 0; ki < 3; ++ki) {
    int yn = y - ki + 1;
    if (yn < 0 || yn >= HH) continue;
#pragma unroll
    for (int kj = 0; kj < 3; ++kj) {
      int xn = x - kj + 1;
      if (xn < 0 || xn >= WW) continue;
      cnt += 1.f;
      int m = (int)(0xFFFFFFFFu ^ (unsigned)(keytab[yn * WW + xn] & 0xFFFFFFFFull));
      if (TMODE) {
        int ys = m / WW, xs = m - (m / WW) * WW;
        int sy = ys + ki - 1, sx = xs + kj - 1;
        if (sy >= 0 && sy < HH && sx >= 0 && sx < WW)
          sum += styT[(size_t)(sy * WW + sx) * 128 + c];
      } else {
        sum += (float)Ps[(size_t)m * DDIM + c * 9 + ki * 3 + kj];
      }
    }
  }
  float recon = sum / (cnt + 1e-8f);
  float cv = (float)Pc[(size_t)pix * DDIM + c * 9 + 4];
  float d = cv - recon;
  float sq = d * d;
#pragma unroll
  for (int m = 32; m > 0; m >>= 1) sq += __shfl_down(sq, m, 64);
  __shared__ float wsum[4];
  int lane = threadIdx.x & 63, w = threadIdx.x >> 6;
  if (lane == 0) wsum[w] = sq;
  __syncthreads();
  if (threadIdx.x == 0)
    atomicAdd(out, (wsum[0] + wsum[1] + wsum[2] + wsum[3]) * (1.0f / (float)TOTAL_ELEMS));
}

extern "C" void kernel_launch(void* const* d_in, const int* in_sizes, int n_in,
                              void* d_out, int out_size, void* d_ws, size_t ws_size,
                              hipStream_t stream) {
  const float* content = (const float*)d_in[0];
  const float* stylef = (const float*)d_in[1];
  float* out = (float*)d_out;
  char* ws = (char*)d_ws;

  const size_t PS_OFF = 0;
  const size_t PC_OFF = (size_t)NPIX * DDIM * 2;       // 21,233,664
  const size_t RN_OFF = PC_OFF * 2;                    // 42,467,328
  const size_t KEY_OFF = RN_OFF + (size_t)NPIX * 4;    // 42,504,192
  const size_t ST_OFF = KEY_OFF + (size_t)NPIX * 8;    // 42,577,920
  const size_t END_T = ST_OFF + (size_t)NPIX * 128 * 4;

  __bf16* Ps = (__bf16*)(ws + PS_OFF);
  __bf16* Pc = (__bf16*)(ws + PC_OFF);
  float* rnorm = (float*)(ws + RN_OFF);
  unsigned long long* keytab = (unsigned long long*)(ws + KEY_OFF);
  const bool tmode = ws_size >= END_T;
  float* styT = tmode ? (float*)(ws + ST_OFF) : nullptr;

  hipMemsetAsync(d_out, 0, (size_t)out_size * sizeof(float), stream);
  hipMemsetAsync(keytab, 0, (size_t)NPIX * 8, stream);
  build_patches_kernel<<<dim3(96, 4, 2), 256, 0, stream>>>(stylef, content, Ps, Pc, styT);
  norm_kernel<<<NPIX / 4, 256, 0, stream>>>(Ps, rnorm);
  gemm_argmax_kernel<<<NBLK, 256, 0, stream>>>(Pc, Ps, rnorm, keytab);
  if (tmode)
    recon_mse_kernel<true><<<NPIX / 2, 256, 0, stream>>>(Pc, Ps, styT, keytab, out);
  else
    recon_mse_kernel<false><<<NPIX / 2, 256, 0, stream>>>(Pc, Ps, nullptr, keytab, out);
}

// Round 7
// 269.174 us; speedup vs baseline: 1.5268x; 1.4250x over previous
//
#include <hip/hip_runtime.h>
#include <hip/hip_bf16.h>

#define HH 96
#define WW 96
#define NPIX 9216
#define NCH 128
#define DDIM 1152
#define TOTAL_ELEMS 1179648
#define CG 32
#define DDIAG 9217            // NPIX+1 (diagonal flat step)
#define DROW 884832           // 96*9217

typedef float f32x4 __attribute__((ext_vector_type(4)));
typedef __bf16 bf16x8 __attribute__((ext_vector_type(8)));

__device__ __forceinline__ void gload_lds16(const void* g, void* l) {
  __builtin_amdgcn_global_load_lds((const __attribute__((address_space(1))) void*)g,
                                   (__attribute__((address_space(3))) void*)l, 16, 0, 0);
}

// ======================= NEW PATH (G-factorized) =======================
// G(a,b) = sum_c Ct[a,c]*St[b,c];  dist(n,m) = sum_{delta} G(n+delta, m+delta),
// delta = (di-1)*96 + (dj-1), masked; flat offset = delta*(NPIX+1).

#define GUARD_ELEMS 894064ull                   // >= 97*9217+8, multiple of 8
constexpr size_t G_CORE_ELEMS = (size_t)NPIX * NPIX;
constexpr size_t G_TOT_ELEMS = G_CORE_ELEMS + 2ull * GUARD_ELEMS;
constexpr size_t GBYTES = ((G_TOT_ELEMS * 2 + 255) & ~(size_t)255);
constexpr size_t CT_OFF = GBYTES;
constexpr size_t ST2_OFF = CT_OFF + (size_t)NPIX * NCH * 2;
constexpr size_t STYT_OFF = ST2_OFF + (size_t)NPIX * NCH * 2;
constexpr size_t SS_OFF = STYT_OFF + (size_t)NPIX * NCH * 4;
constexpr size_t RN2_OFF = SS_OFF + (size_t)NPIX * 4;
constexpr size_t KEY2_OFF = RN2_OFF + (size_t)NPIX * 4;
constexpr size_t NEED_NEW = KEY2_OFF + (size_t)NPIX * 8;

// features [c][pix] f32 -> [pix][c] bf16 (+ styT f32 for style)
__global__ __launch_bounds__(256)
void transpose_kernel(const float* __restrict__ style_f, const float* __restrict__ content_f,
                      __bf16* __restrict__ St, __bf16* __restrict__ Ct,
                      float* __restrict__ styT) {
  __shared__ float ftile[NCH][97];
  const int y = blockIdx.x;
  const bool is_style = (blockIdx.y == 0);
  const float* f = is_style ? style_f : content_f;
  __bf16* P = is_style ? St : Ct;
  const int tid = threadIdx.x;
  for (int i = tid; i < NCH * WW; i += 256) {
    int c = i / WW, x = i - (i / WW) * WW;
    ftile[c][x] = f[(size_t)c * NPIX + y * WW + x];
  }
  __syncthreads();
  for (int j = tid; j < WW * NCH; j += 256) {
    int x = j >> 7, c = j & 127;
    float v = ftile[c][x];
    P[(size_t)(y * WW + x) * NCH + c] = (__bf16)v;
    if (is_style) styT[(size_t)(y * WW + x) * NCH + c] = v;
  }
}

// per-pixel channel sum-of-squares from f32 styT (wave per pixel)
__global__ __launch_bounds__(256)
void norm2_kernel(const float* __restrict__ styT, float* __restrict__ ss) {
  const int p = blockIdx.x * 4 + (threadIdx.x >> 6);
  const int lane = threadIdx.x & 63;
  float2 v = ((const float2*)(styT + (size_t)p * NCH))[lane];
  float s = v.x * v.x + v.y * v.y;
#pragma unroll
  for (int m = 1; m < 64; m <<= 1) s += __shfl_xor(s, m, 64);
  if (lane == 0) ss[p] = s;
}

// patch norm: masked 3x3 box-sum of ss -> rnorm = 1/max(sqrt, 1e-12)
__global__ __launch_bounds__(256)
void boxnorm_kernel(const float* __restrict__ ss, float* __restrict__ rnorm) {
  int m = blockIdx.x * 256 + threadIdx.x;
  int ym = m / WW, xm = m - (m / WW) * WW;
  float s = 0.f;
#pragma unroll
  for (int di = -1; di <= 1; ++di) {
    int yy = ym + di;
    if (yy < 0 || yy >= HH) continue;
#pragma unroll
    for (int dj = -1; dj <= 1; ++dj) {
      int xx = xm + dj;
      if (xx < 0 || xx >= WW) continue;
      s += ss[yy * WW + xx];
    }
  }
  rnorm[m] = 1.0f / fmaxf(sqrtf(s), 1e-12f);
}

// G-GEMM: 128x128 tile, K=128 single shot. 4 waves (2Mx2N), wave 64x64.
__global__ __launch_bounds__(256, 2)
void ggemm_kernel(const __bf16* __restrict__ Ct, const __bf16* __restrict__ St,
                  unsigned short* __restrict__ Gg) {
  __shared__ char smem[65536];  // A 32KB + B 32KB; reused for bf16 repack
  const int tid = threadIdx.x;
  const int lane = tid & 63, wid = tid >> 6;
  const int l15 = lane & 15, lg = lane >> 4;
  const int wm = wid >> 1, wn = wid & 1;
  const int n0 = blockIdx.x * 128, m0 = blockIdx.y * 128;

  {  // stage A,B with slot-XOR swizzle (phys slot = logical ^ (row&7))
    const int r = tid >> 4, p = tid & 15;
    const int l = p ^ (r & 7);
    const __bf16* sa = Ct + (size_t)(n0 + r) * NCH + l * 8;
    const __bf16* sb = St + (size_t)(m0 + r) * NCH + l * 8;
    char* d = smem + tid * 16;
#pragma unroll
    for (int i = 0; i < 8; ++i) {
      gload_lds16(sa + (size_t)16 * i * NCH, d + 4096 * i);
      gload_lds16(sb + (size_t)16 * i * NCH, d + 32768 + 4096 * i);
    }
  }
  __syncthreads();

  f32x4 acc[4][4];
#pragma unroll
  for (int mf = 0; mf < 4; ++mf)
#pragma unroll
    for (int nf = 0; nf < 4; ++nf) {
      f32x4 z = {0.f, 0.f, 0.f, 0.f};
      acc[mf][nf] = z;
    }

#pragma unroll
  for (int ks = 0; ks < 4; ++ks) {
    bf16x8 af[4], bb[4];
#pragma unroll
    for (int mf = 0; mf < 4; ++mf) {
      int row = wm * 64 + mf * 16 + l15;
      int phys = (ks * 4 + lg) ^ (row & 7);
      af[mf] = __builtin_bit_cast(bf16x8, *(const int4*)(smem + row * 256 + phys * 16));
    }
#pragma unroll
    for (int nf = 0; nf < 4; ++nf) {
      int row = wn * 64 + nf * 16 + l15;
      int phys = (ks * 4 + lg) ^ (row & 7);
      bb[nf] = __builtin_bit_cast(bf16x8, *(const int4*)(smem + 32768 + row * 256 + phys * 16));
    }
#pragma unroll
    for (int mf = 0; mf < 4; ++mf)
#pragma unroll
      for (int nf = 0; nf < 4; ++nf)
        acc[mf][nf] = __builtin_amdgcn_mfma_f32_16x16x32_bf16(af[mf], bb[nf], acc[mf][nf], 0, 0, 0);
  }
  __syncthreads();  // all LDS reads done before repack overwrite

  // repack acc -> bf16 LDS [128][136], then coalesced dwordx4 stores
#pragma unroll
  for (int mf = 0; mf < 4; ++mf)
#pragma unroll
    for (int nf = 0; nf < 4; ++nf)
#pragma unroll
      for (int r = 0; r < 4; ++r) {
        int row = wm * 64 + mf * 16 + lg * 4 + r;
        int col = wn * 64 + nf * 16 + l15;
        *(__bf16*)(smem + (row * 136 + col) * 2) = (__bf16)acc[mf][nf][r];
      }
  __syncthreads();
  const size_t gbase = GUARD_ELEMS + (size_t)n0 * NPIX + m0;
#pragma unroll
  for (int j = 0; j < 8; ++j) {
    int idx = j * 256 + tid;
    int row = idx >> 4, ch = idx & 15;
    int4 v = *(const int4*)(smem + (row * 136 + ch * 8) * 2);
    *(int4*)(Gg + gbase + (size_t)row * NPIX + ch * 8) = v;
  }
}

// dist + argmax: 648 blocks = 8 XCD-groups x (9 n-tiles x 9 m-splits).
// Wave owns 32 n (shared by lanes); lane owns 8 consecutive m; 9 diagonal taps.
// dj=0 taps aligned int4; dj=+-1 taps = aligned int4 + 1 ushort, realigned in-register.
__global__ __launch_bounds__(256)
void dist_argmax_kernel(const unsigned short* __restrict__ Gg, const float* __restrict__ rnorm,
                        unsigned long long* __restrict__ keytab) {
  const int bid = blockIdx.x;
  const int xcd = bid & 7;
  const int local = bid >> 3;                 // 0..80
  const int nt = xcd * 9 + (local % 9);       // 0..71
  const int ms = local / 9;                   // 0..8
  const int w = threadIdx.x >> 6;
  const int lane = threadIdx.x & 63;
  const int nbase = nt * 128 + w * 32;

  for (int c = 0; c < 2; ++c) {
    const int m8 = ms * 1024 + c * 512 + lane * 8;
    const int ym = m8 / WW;
    const int x8 = m8 - ym * WW;               // multiple of 8 -> no x-wrap in the 8
    const float rm0 = (ym >= 1) ? 1.f : 0.f;
    const float rm2 = (ym <= 94) ? 1.f : 0.f;
    const float e0 = (x8 == 0) ? 0.f : 1.f;    // m-col edge for j=0 of dj=-1 runs
    const float e7 = (x8 == 88) ? 0.f : 1.f;   // m-col edge for j=7 of dj=+1 runs
    float rnv[8];
    *(f32x4*)(rnv) = *(const f32x4*)(rnorm + m8);
    *(f32x4*)(rnv + 4) = *(const f32x4*)(rnorm + m8 + 4);
    const int ib = nbase * NPIX + m8 + (int)GUARD_ELEMS;

#pragma unroll 2
    for (int s = 0; s < 32; ++s) {
      const int n = nbase + s;
      const int yn = n / WW;
      const int xn = n - yn * WW;
      const float cn0 = (xn >= 1) ? 1.f : 0.f;
      const float cn2 = (xn <= 94) ? 1.f : 0.f;
      float rbv[3];
      rbv[0] = (yn >= 1) ? rm0 : 0.f;
      rbv[1] = 1.f;
      rbv[2] = (yn <= 94) ? rm2 : 0.f;
      const int base = ib + s * NPIX;
      float d[8] = {0.f, 0.f, 0.f, 0.f, 0.f, 0.f, 0.f, 0.f};
#pragma unroll
      for (int t = 0; t < 3; ++t) {            // di = t-1
        const int rbase = base + (t - 1) * DROW;
        const float wc = rbv[t];
        const float wl = wc * cn0, wl0 = wl * e0;
        const float wr = wc * cn2, wr7 = wr * e7;
        {  // center tap (dj=0), aligned
          int4 L = *(const int4*)(Gg + rbase);
          unsigned r0 = (unsigned)L.x, r1 = (unsigned)L.y, r2 = (unsigned)L.z, r3 = (unsigned)L.w;
          d[0] = fmaf(wc, __uint_as_float(r0 << 16), d[0]);
          d[1] = fmaf(wc, __uint_as_float(r0 & 0xffff0000u), d[1]);
          d[2] = fmaf(wc, __uint_as_float(r1 << 16), d[2]);
          d[3] = fmaf(wc, __uint_as_float(r1 & 0xffff0000u), d[3]);
          d[4] = fmaf(wc, __uint_as_float(r2 << 16), d[4]);
          d[5] = fmaf(wc, __uint_as_float(r2 & 0xffff0000u), d[5]);
          d[6] = fmaf(wc, __uint_as_float(r3 << 16), d[6]);
          d[7] = fmaf(wc, __uint_as_float(r3 & 0xffff0000u), d[7]);
        }
        {  // left tap (dj=-1): start s0 = rbase-9217 (== 7 mod 8); P + L[s0+1..s0+8]
          const int s0 = rbase - DDIAG;
          unsigned P = Gg[s0];
          int4 L = *(const int4*)(Gg + s0 + 1);
          unsigned Lx = (unsigned)L.x, Ly = (unsigned)L.y, Lz = (unsigned)L.z, Lw = (unsigned)L.w;
          unsigned r0 = (P & 0xffffu) | (Lx << 16);
          unsigned r1 = (Lx >> 16) | (Ly << 16);
          unsigned r2 = (Ly >> 16) | (Lz << 16);
          unsigned r3 = (Lz >> 16) | (Lw << 16);
          d[0] = fmaf(wl0, __uint_as_float(r0 << 16), d[0]);
          d[1] = fmaf(wl, __uint_as_float(r0 & 0xffff0000u), d[1]);
          d[2] = fmaf(wl, __uint_as_float(r1 << 16), d[2]);
          d[3] = fmaf(wl, __uint_as_float(r1 & 0xffff0000u), d[3]);
          d[4] = fmaf(wl, __uint_as_float(r2 << 16), d[4]);
          d[5] = fmaf(wl, __uint_as_float(r2 & 0xffff0000u), d[5]);
          d[6] = fmaf(wl, __uint_as_float(r3 << 16), d[6]);
          d[7] = fmaf(wl, __uint_as_float(r3 & 0xffff0000u), d[7]);
        }
        {  // right tap (dj=+1): start s0 = rbase+9217 (== 1 mod 8); L[s0-1..s0+6] + X
          const int s0 = rbase + DDIAG;
          int4 L = *(const int4*)(Gg + s0 - 1);
          unsigned X = Gg[s0 + 7];
          unsigned Lx = (unsigned)L.x, Ly = (unsigned)L.y, Lz = (unsigned)L.z, Lw = (unsigned)L.w;
          unsigned r0 = (Lx >> 16) | (Ly << 16);
          unsigned r1 = (Ly >> 16) | (Lz << 16);
          unsigned r2 = (Lz >> 16) | (Lw << 16);
          unsigned r3 = (Lw >> 16) | (X << 16);
          d[0] = fmaf(wr, __uint_as_float(r0 << 16), d[0]);
          d[1] = fmaf(wr, __uint_as_float(r0 & 0xffff0000u), d[1]);
          d[2] = fmaf(wr, __uint_as_float(r1 << 16), d[2]);
          d[3] = fmaf(wr, __uint_as_float(r1 & 0xffff0000u), d[3]);
          d[4] = fmaf(wr, __uint_as_float(r2 << 16), d[4]);
          d[5] = fmaf(wr, __uint_as_float(r2 & 0xffff0000u), d[5]);
          d[6] = fmaf(wr, __uint_as_float(r3 << 16), d[6]);
          d[7] = fmaf(wr7, __uint_as_float(r3 & 0xffff0000u), d[7]);
        }
      }
      // score + argmax (ascending m; strict > keeps first max)
      float bv = d[0] * rnv[0];
      int bj = m8;
#pragma unroll
      for (int j = 1; j < 8; ++j) {
        float xsc = d[j] * rnv[j];
        if (xsc > bv) { bv = xsc; bj = m8 + j; }
      }
#pragma unroll
      for (int mm = 1; mm < 64; mm <<= 1) {
        float ov = __shfl_xor(bv, mm, 64);
        int oi = __shfl_xor(bj, mm, 64);
        if (ov > bv || (ov == bv && oi < bj)) { bv = ov; bj = oi; }
      }
      if (lane == 0) {
        unsigned u = __float_as_uint(bv);
        u ^= (unsigned)((int)u >> 31) | 0x80000000u;
        unsigned long long key =
            ((unsigned long long)u << 32) | (unsigned)(0xFFFFFFFFu ^ (unsigned)bj);
        atomicMax(keytab + n, key);
      }
    }
  }
}

// recon+MSE (new path): content from Ct bf16, style from styT f32
__global__ __launch_bounds__(256)
void recon_mse2_kernel(const __bf16* __restrict__ Ct, const float* __restrict__ styT,
                       const unsigned long long* __restrict__ keytab, float* __restrict__ out) {
  const int pix = blockIdx.x * 2 + (threadIdx.x >> 7);
  const int c = threadIdx.x & 127;
  const int y = pix / WW, x = pix - (pix / WW) * WW;
  float sum = 0.f, cnt = 0.f;
#pragma unroll
  for (int ki = 0; ki < 3; ++ki) {
    int yn = y - ki + 1;
    if (yn < 0 || yn >= HH) continue;
#pragma unroll
    for (int kj = 0; kj < 3; ++kj) {
      int xn = x - kj + 1;
      if (xn < 0 || xn >= WW) continue;
      cnt += 1.f;
      int m = (int)(0xFFFFFFFFu ^ (unsigned)(keytab[yn * WW + xn] & 0xFFFFFFFFull));
      int ys = m / WW, xs = m - (m / WW) * WW;
      int sy = ys + ki - 1, sx = xs + kj - 1;
      if (sy >= 0 && sy < HH && sx >= 0 && sx < WW)
        sum += styT[(size_t)(sy * WW + sx) * NCH + c];
    }
  }
  float recon = sum / (cnt + 1e-8f);
  float cv = (float)Ct[(size_t)pix * NCH + c];
  float diff = cv - recon;
  float sq = diff * diff;
#pragma unroll
  for (int m = 32; m > 0; m >>= 1) sq += __shfl_down(sq, m, 64);
  __shared__ float wsum[4];
  int lane = threadIdx.x & 63, w = threadIdx.x >> 6;
  if (lane == 0) wsum[w] = sq;
  __syncthreads();
  if (threadIdx.x == 0)
    atomicAdd(out, (wsum[0] + wsum[1] + wsum[2] + wsum[3]) * (1.0f / (float)TOTAL_ELEMS));
}

// ======================= OLD PATH (round-3, fallback) =======================
__global__ __launch_bounds__(256)
void build_patches_old(const float* __restrict__ style_f, const float* __restrict__ content_f,
                       __bf16* __restrict__ Ps, __bf16* __restrict__ Pc) {
  __shared__ float ftile[CG][3][104];
  const int y = blockIdx.x;
  const int cg = blockIdx.y;
  const bool is_style = (blockIdx.z == 0);
  const float* f = is_style ? style_f : content_f;
  __bf16* P = is_style ? Ps : Pc;
  const int tid = threadIdx.x;
  for (int i = tid; i < CG * 3 * 96; i += 256) {
    int cl = i / 288, rem = i - cl * 288;
    int yy = rem / 96, xx = rem - yy * 96;
    int gy = y + yy - 1;
    float v = (gy >= 0 && gy < HH) ? f[(size_t)(cg * CG + cl) * NPIX + gy * WW + xx] : 0.f;
    ftile[cl][yy][xx] = v;
  }
  __syncthreads();
  for (int j = tid; j < 96 * 36; j += 256) {
    int px = j / 36, wi = j - px * 36;
    bf16x8 tmp;
#pragma unroll
    for (int u = 0; u < 8; ++u) {
      int e = wi * 8 + u;
      int cl = e / 9, t = e - cl * 9;
      int ki = t / 3, kj = t - ki * 3;
      int xx = px + kj - 1;
      float v = (xx >= 0 && xx < WW) ? ftile[cl][ki][xx] : 0.f;
      tmp[u] = (__bf16)v;
    }
    *(bf16x8*)(P + (size_t)(y * WW + px) * DDIM + cg * 288 + wi * 8) = tmp;
  }
}

__global__ __launch_bounds__(256)
void norm_old(const __bf16* __restrict__ Ps, float* __restrict__ rnorm) {
  const int n = blockIdx.x * 4 + (threadIdx.x >> 6);
  const int lane = threadIdx.x & 63;
  const bf16x8* row = (const bf16x8*)(Ps + (size_t)n * DDIM);
  float ss = 0.f;
#pragma unroll
  for (int i = 0; i < 3; ++i) {
    int idx = i * 64 + lane;
    if (idx < 144) {
      bf16x8 v = row[idx];
#pragma unroll
      for (int u = 0; u < 8; ++u) { float x = (float)v[u]; ss += x * x; }
    }
  }
#pragma unroll
  for (int m = 1; m < 64; m <<= 1) ss += __shfl_xor(ss, m, 64);
  if (lane == 0) rnorm[n] = 1.0f / fmaxf(sqrtf(ss), 1e-12f);
}

__global__ __launch_bounds__(256, 2)
void gemm_old(const __bf16* __restrict__ Pc, const __bf16* __restrict__ Ps,
              const float* __restrict__ rnorm, unsigned long long* __restrict__ keytab) {
  __shared__ int4 smem4[4608];
  char* smem = (char*)smem4;
  const int tid = threadIdx.x;
  const int lane = tid & 63;
  const int wid = tid >> 6;
  const int l15 = lane & 15;
  const int lg = lane >> 4;
  const int wm = wid >> 1;
  const int wn = wid & 1;
  const int orig = blockIdx.x;
  const int swz = (orig & 7) * 324 + (orig >> 3);
  const int mt = swz / 72;
  const int nt = swz - mt * 72;
  const int bm0 = mt * 256;
  const int sbase = nt * 128;
  const int srow = tid >> 2;
  const int sg = (tid & 3) ^ ((srow >> 1) & 3);
  const __bf16* pa = Pc + (size_t)(bm0 + srow) * DDIM + sg * 8;
  const __bf16* pb = Ps + (size_t)(sbase + srow) * DDIM + sg * 8;
  const int sdst = tid * 16;
  auto stage = [&](int buf, int kt) {
    char* la = smem + buf * 24576 + sdst;
    const int ko = kt * 32;
#pragma unroll
    for (int i = 0; i < 4; ++i) gload_lds16(pa + (size_t)i * 64 * DDIM + ko, la + i * 4096);
#pragma unroll
    for (int j = 0; j < 2; ++j) gload_lds16(pb + (size_t)j * 64 * DDIM + ko, la + 16384 + j * 4096);
  };
  const int sx = (lg ^ ((l15 >> 1) & 3)) << 4;
  int aoff[8], boff[4];
#pragma unroll
  for (int mf = 0; mf < 8; ++mf) aoff[mf] = (wm * 128 + mf * 16 + l15) * 64 + sx;
#pragma unroll
  for (int nf = 0; nf < 4; ++nf) boff[nf] = 16384 + (wn * 64 + nf * 16 + l15) * 64 + sx;
  f32x4 acc[8][4];
#pragma unroll
  for (int mf = 0; mf < 8; ++mf)
#pragma unroll
    for (int nf = 0; nf < 4; ++nf) {
      f32x4 z = {0.f, 0.f, 0.f, 0.f};
      acc[mf][nf] = z;
    }
  auto compute = [&](int buf) {
    const char* bp = smem + buf * 24576;
    bf16x8 af[8], bfr[4];
#pragma unroll
    for (int mf = 0; mf < 8; ++mf) af[mf] = __builtin_bit_cast(bf16x8, *(const int4*)(bp + aoff[mf]));
#pragma unroll
    for (int nf = 0; nf < 4; ++nf) bfr[nf] = __builtin_bit_cast(bf16x8, *(const int4*)(bp + boff[nf]));
    __builtin_amdgcn_s_setprio(1);
#pragma unroll
    for (int mf = 0; mf < 8; ++mf)
#pragma unroll
      for (int nf = 0; nf < 4; ++nf)
        acc[mf][nf] = __builtin_amdgcn_mfma_f32_16x16x32_bf16(af[mf], bfr[nf], acc[mf][nf], 0, 0, 0);
    __builtin_amdgcn_s_setprio(0);
  };
  stage(0, 0);
  stage(1, 1);
  int sb = 2, cb = 0;
  for (int kt = 0; kt < 34; ++kt) {
    stage(sb, kt + 2);
    sb = (sb == 2) ? 0 : sb + 1;
    asm volatile("s_waitcnt vmcnt(12)" ::: "memory");
    __builtin_amdgcn_s_barrier();
    __builtin_amdgcn_sched_barrier(0);
    compute(cb);
    __builtin_amdgcn_s_barrier();
    cb = (cb == 2) ? 0 : cb + 1;
  }
  asm volatile("s_waitcnt vmcnt(6)" ::: "memory");
  __builtin_amdgcn_s_barrier();
  __builtin_amdgcn_sched_barrier(0);
  compute(cb);
  cb = (cb == 2) ? 0 : cb + 1;
  asm volatile("s_waitcnt vmcnt(0)" ::: "memory");
  __builtin_amdgcn_s_barrier();
  __builtin_amdgcn_sched_barrier(0);
  compute(cb);
  float rn[4];
#pragma unroll
  for (int nf = 0; nf < 4; ++nf) rn[nf] = rnorm[sbase + wn * 64 + nf * 16 + l15];
#pragma unroll
  for (int mf = 0; mf < 8; ++mf)
#pragma unroll
    for (int r = 0; r < 4; ++r) {
      float v = -3.0e38f;
      int bi = 0;
#pragma unroll
      for (int nf = 0; nf < 4; ++nf) {
        float x = acc[mf][nf][r] * rn[nf];
        int col = sbase + wn * 64 + nf * 16 + l15;
        if (x > v) { v = x; bi = col; }
      }
#pragma unroll
      for (int m = 1; m < 16; m <<= 1) {
        float ov = __shfl_xor(v, m, 64);
        int oi = __shfl_xor(bi, m, 64);
        if (ov > v || (ov == v && oi < bi)) { v = ov; bi = oi; }
      }
      if (l15 == 0) {
        int row = bm0 + wm * 128 + mf * 16 + lg * 4 + r;
        unsigned u = __float_as_uint(v);
        u ^= (unsigned)((int)u >> 31) | 0x80000000u;
        unsigned long long key = ((unsigned long long)u << 32) | (unsigned)(0xFFFFFFFFu ^ (unsigned)bi);
        atomicMax(keytab + row, key);
      }
    }
}

__global__ __launch_bounds__(256)
void recon_old(const __bf16* __restrict__ Pc, const __bf16* __restrict__ Ps,
               const unsigned long long* __restrict__ keytab, float* __restrict__ out) {
  const int pix = blockIdx.x * 2 + (threadIdx.x >> 7);
  const int c = threadIdx.x & 127;
  const int y = pix / WW, x = pix - (pix / WW) * WW;
  float sum = 0.f, cnt = 0.f;
#pragma unroll
  for (int ki = 0; ki < 3; ++ki) {
    int yn = y - ki + 1;
    if (yn < 0 || yn >= HH) continue;
#pragma unroll
    for (int kj = 0; kj < 3; ++kj) {
      int xn = x - kj + 1;
      if (xn < 0 || xn >= WW) continue;
      cnt += 1.f;
      int m = (int)(0xFFFFFFFFu ^ (unsigned)(keytab[yn * WW + xn] & 0xFFFFFFFFull));
      sum += (float)Ps[(size_t)m * DDIM + c * 9 + ki * 3 + kj];
    }
  }
  float recon = sum / (cnt + 1e-8f);
  float cv = (float)Pc[(size_t)pix * DDIM + c * 9 + 4];
  float diff = cv - recon;
  float sq = diff * diff;
#pragma unroll
  for (int m = 32; m > 0; m >>= 1) sq += __shfl_down(sq, m, 64);
  __shared__ float wsum[4];
  int lane = threadIdx.x & 63, w = threadIdx.x >> 6;
  if (lane == 0) wsum[w] = sq;
  __syncthreads();
  if (threadIdx.x == 0)
    atomicAdd(out, (wsum[0] + wsum[1] + wsum[2] + wsum[3]) * (1.0f / (float)TOTAL_ELEMS));
}

extern "C" void kernel_launch(void* const* d_in, const int* in_sizes, int n_in,
                              void* d_out, int out_size, void* d_ws, size_t ws_size,
                              hipStream_t stream) {
  const float* content = (const float*)d_in[0];
  const float* stylef = (const float*)d_in[1];
  float* out = (float*)d_out;
  char* ws = (char*)d_ws;

  hipMemsetAsync(d_out, 0, (size_t)out_size * sizeof(float), stream);

  if (ws_size >= NEED_NEW) {
    unsigned short* Gg = (unsigned short*)ws;
    __bf16* Ct = (__bf16*)(ws + CT_OFF);
    __bf16* St = (__bf16*)(ws + ST2_OFF);
    float* styT = (float*)(ws + STYT_OFF);
    float* ss = (float*)(ws + SS_OFF);
    float* rnorm = (float*)(ws + RN2_OFF);
    unsigned long long* keytab = (unsigned long long*)(ws + KEY2_OFF);

    hipMemsetAsync(keytab, 0, (size_t)NPIX * 8, stream);
    // zero guard bands: masked (x0) taps must not read NaN-capable poison
    hipMemsetAsync(Gg, 0, (size_t)GUARD_ELEMS * 2, stream);
    hipMemsetAsync(Gg + GUARD_ELEMS + G_CORE_ELEMS, 0, (size_t)GUARD_ELEMS * 2, stream);
    transpose_kernel<<<dim3(96, 2), 256, 0, stream>>>(stylef, content, St, Ct, styT);
    norm2_kernel<<<NPIX / 4, 256, 0, stream>>>(styT, ss);
    boxnorm_kernel<<<NPIX / 256, 256, 0, stream>>>(ss, rnorm);
    ggemm_kernel<<<dim3(72, 72), 256, 0, stream>>>(Ct, St, Gg);
    dist_argmax_kernel<<<648, 256, 0, stream>>>(Gg, rnorm, keytab);
    recon_mse2_kernel<<<NPIX / 2, 256, 0, stream>>>(Ct, styT, keytab, out);
  } else {
    const size_t PS_OFF = 0;
    const size_t PC_OFF = (size_t)NPIX * DDIM * 2;
    const size_t RN_OFF = PC_OFF * 2;
    const size_t KEY_OFF = RN_OFF + (size_t)NPIX * 4;
    __bf16* Ps = (__bf16*)(ws + PS_OFF);
    __bf16* Pc = (__bf16*)(ws + PC_OFF);
    float* rnorm = (float*)(ws + RN_OFF);
    unsigned long long* keytab = (unsigned long long*)(ws + KEY_OFF);
    hipMemsetAsync(keytab, 0, (size_t)NPIX * 8, stream);
    build_patches_old<<<dim3(96, 4, 2), 256, 0, stream>>>(stylef, content, Ps, Pc);
    norm_old<<<NPIX / 4, 256, 0, stream>>>(Ps, rnorm);
    gemm_old<<<2592, 256, 0, stream>>>(Pc, Ps, rnorm, keytab);
    recon_old<<<NPIX / 2, 256, 0, stream>>>(Pc, Ps, keytab, out);
  }
}

// Round 8
// 255.804 us; speedup vs baseline: 1.6066x; 1.0523x over previous
//
#include <hip/hip_runtime.h>
#include <hip/hip_bf16.h>

#define HH 96
#define WW 96
#define NPIX 9216
#define NCH 128
#define DDIM 1152
#define TOTAL_ELEMS 1179648
#define CG 32
#define DDIAG 9217            // NPIX+1 (diagonal flat step)
#define DROW 884832           // 96*9217

typedef float f32x4 __attribute__((ext_vector_type(4)));
typedef __bf16 bf16x8 __attribute__((ext_vector_type(8)));
typedef _Float16 half8 __attribute__((ext_vector_type(8)));

__device__ __forceinline__ void gload_lds16(const void* g, void* l) {
  __builtin_amdgcn_global_load_lds((const __attribute__((address_space(1))) void*)g,
                                   (__attribute__((address_space(3))) void*)l, 16, 0, 0);
}

// ======================= NEW PATH (G-factorized, f16) =======================
// G(a,b) = sum_c Ct[a,c]*St[b,c];  dist(n,m) = sum_{delta} G(n+delta, m+delta),
// delta = (di-1)*96 + (dj-1), masked; flat offset = delta*(NPIX+1).

#define GUARD_ELEMS 894064ull                   // >= 97*9217+8, multiple of 8
constexpr size_t G_CORE_ELEMS = (size_t)NPIX * NPIX;
constexpr size_t G_TOT_ELEMS = G_CORE_ELEMS + 2ull * GUARD_ELEMS;
constexpr size_t GBYTES = ((G_TOT_ELEMS * 2 + 255) & ~(size_t)255);
constexpr size_t CT_OFF = GBYTES;
constexpr size_t ST2_OFF = CT_OFF + (size_t)NPIX * NCH * 2;
constexpr size_t STYT_OFF = ST2_OFF + (size_t)NPIX * NCH * 2;
constexpr size_t SS_OFF = STYT_OFF + (size_t)NPIX * NCH * 4;
constexpr size_t RN2_OFF = SS_OFF + (size_t)NPIX * 4;
constexpr size_t KEY2_OFF = RN2_OFF + (size_t)NPIX * 4;
constexpr size_t NEED_NEW = KEY2_OFF + (size_t)NPIX * 8;

// features [c][pix] f32 -> [pix][c] f16 (+ styT f32 for style)
__global__ __launch_bounds__(256)
void transpose_kernel(const float* __restrict__ style_f, const float* __restrict__ content_f,
                      _Float16* __restrict__ St, _Float16* __restrict__ Ct,
                      float* __restrict__ styT) {
  __shared__ float ftile[NCH][97];
  const int y = blockIdx.x;
  const bool is_style = (blockIdx.y == 0);
  const float* f = is_style ? style_f : content_f;
  _Float16* P = is_style ? St : Ct;
  const int tid = threadIdx.x;
  for (int i = tid; i < NCH * WW; i += 256) {
    int c = i / WW, x = i - (i / WW) * WW;
    ftile[c][x] = f[(size_t)c * NPIX + y * WW + x];
  }
  __syncthreads();
  for (int j = tid; j < WW * NCH; j += 256) {
    int x = j >> 7, c = j & 127;
    float v = ftile[c][x];
    P[(size_t)(y * WW + x) * NCH + c] = (_Float16)v;
    if (is_style) styT[(size_t)(y * WW + x) * NCH + c] = v;
  }
}

// per-pixel channel sum-of-squares from f32 styT (wave per pixel)
__global__ __launch_bounds__(256)
void norm2_kernel(const float* __restrict__ styT, float* __restrict__ ss) {
  const int p = blockIdx.x * 4 + (threadIdx.x >> 6);
  const int lane = threadIdx.x & 63;
  float2 v = ((const float2*)(styT + (size_t)p * NCH))[lane];
  float s = v.x * v.x + v.y * v.y;
#pragma unroll
  for (int m = 1; m < 64; m <<= 1) s += __shfl_xor(s, m, 64);
  if (lane == 0) ss[p] = s;
}

// patch norm: masked 3x3 box-sum of ss -> rnorm = 1/max(sqrt, 1e-12)
__global__ __launch_bounds__(256)
void boxnorm_kernel(const float* __restrict__ ss, float* __restrict__ rnorm) {
  int m = blockIdx.x * 256 + threadIdx.x;
  int ym = m / WW, xm = m - (m / WW) * WW;
  float s = 0.f;
#pragma unroll
  for (int di = -1; di <= 1; ++di) {
    int yy = ym + di;
    if (yy < 0 || yy >= HH) continue;
#pragma unroll
    for (int dj = -1; dj <= 1; ++dj) {
      int xx = xm + dj;
      if (xx < 0 || xx >= WW) continue;
      s += ss[yy * WW + xx];
    }
  }
  rnorm[m] = 1.0f / fmaxf(sqrtf(s), 1e-12f);
}

// G-GEMM: 128x128 tile, K=128 single shot, f16 MFMA. 4 waves (2Mx2N), wave 64x64.
__global__ __launch_bounds__(256, 2)
void ggemm_kernel(const _Float16* __restrict__ Ct, const _Float16* __restrict__ St,
                  unsigned short* __restrict__ Gg) {
  __shared__ char smem[65536];  // A 32KB + B 32KB; reused for f16 repack
  const int tid = threadIdx.x;
  const int lane = tid & 63, wid = tid >> 6;
  const int l15 = lane & 15, lg = lane >> 4;
  const int wm = wid >> 1, wn = wid & 1;
  const int n0 = blockIdx.x * 128, m0 = blockIdx.y * 128;

  {  // stage A,B with slot-XOR swizzle (phys slot = logical ^ (row&7))
    const int r = tid >> 4, p = tid & 15;
    const int l = p ^ (r & 7);
    const _Float16* sa = Ct + (size_t)(n0 + r) * NCH + l * 8;
    const _Float16* sb = St + (size_t)(m0 + r) * NCH + l * 8;
    char* d = smem + tid * 16;
#pragma unroll
    for (int i = 0; i < 8; ++i) {
      gload_lds16(sa + (size_t)16 * i * NCH, d + 4096 * i);
      gload_lds16(sb + (size_t)16 * i * NCH, d + 32768 + 4096 * i);
    }
  }
  __syncthreads();

  f32x4 acc[4][4];
#pragma unroll
  for (int mf = 0; mf < 4; ++mf)
#pragma unroll
    for (int nf = 0; nf < 4; ++nf) {
      f32x4 z = {0.f, 0.f, 0.f, 0.f};
      acc[mf][nf] = z;
    }

#pragma unroll
  for (int ks = 0; ks < 4; ++ks) {
    half8 af[4], bb[4];
#pragma unroll
    for (int mf = 0; mf < 4; ++mf) {
      int row = wm * 64 + mf * 16 + l15;
      int phys = (ks * 4 + lg) ^ (row & 7);
      af[mf] = __builtin_bit_cast(half8, *(const int4*)(smem + row * 256 + phys * 16));
    }
#pragma unroll
    for (int nf = 0; nf < 4; ++nf) {
      int row = wn * 64 + nf * 16 + l15;
      int phys = (ks * 4 + lg) ^ (row & 7);
      bb[nf] = __builtin_bit_cast(half8, *(const int4*)(smem + 32768 + row * 256 + phys * 16));
    }
#pragma unroll
    for (int mf = 0; mf < 4; ++mf)
#pragma unroll
      for (int nf = 0; nf < 4; ++nf)
        acc[mf][nf] = __builtin_amdgcn_mfma_f32_16x16x32_f16(af[mf], bb[nf], acc[mf][nf], 0, 0, 0);
  }
  __syncthreads();  // all LDS reads done before repack overwrite

  // repack acc -> f16 LDS [128][136], then coalesced dwordx4 stores
#pragma unroll
  for (int mf = 0; mf < 4; ++mf)
#pragma unroll
    for (int nf = 0; nf < 4; ++nf)
#pragma unroll
      for (int r = 0; r < 4; ++r) {
        int row = wm * 64 + mf * 16 + lg * 4 + r;
        int col = wn * 64 + nf * 16 + l15;
        *(_Float16*)(smem + (row * 136 + col) * 2) = (_Float16)acc[mf][nf][r];
      }
  __syncthreads();
  const size_t gbase = GUARD_ELEMS + (size_t)n0 * NPIX + m0;
#pragma unroll
  for (int j = 0; j < 8; ++j) {
    int idx = j * 256 + tid;
    int row = idx >> 4, ch = idx & 15;
    int4 v = *(const int4*)(smem + (row * 136 + ch * 8) * 2);
    *(int4*)(Gg + gbase + (size_t)row * NPIX + ch * 8) = v;
  }
}

// dist + argmax: 2592 blocks = 8 XCDs x 9 n-tiles x 18 m-splits x 2 s-halves.
// Wave owns 32 n (16 per s-half); lane owns 8 consecutive m; 9 diagonal f16 taps
// consumed directly via fma_mix (no unpack/realign ALU).
__global__ __launch_bounds__(256)
void dist_argmax_kernel(const _Float16* __restrict__ Gg, const float* __restrict__ rnorm,
                        unsigned long long* __restrict__ keytab) {
  const int bid = blockIdx.x;
  const int xcd = bid & 7;
  const int local = bid >> 3;                 // 0..323
  const int nt = xcd * 9 + (local % 9);       // 0..71
  const int rest = local / 9;                 // 0..35
  const int ms = rest % 18;                   // 0..17
  const int sh = rest / 18;                   // 0..1
  const int w = threadIdx.x >> 6;
  const int lane = threadIdx.x & 63;
  const int nbase = nt * 128 + w * 32;

  const int m8 = ms * 512 + lane * 8;
  const int ym = m8 / WW;
  const int x8 = m8 - ym * WW;               // multiple of 8 -> no x-wrap in the 8
  const float rm0 = (ym >= 1) ? 1.f : 0.f;
  const float rm2 = (ym <= 94) ? 1.f : 0.f;
  const float e0 = (x8 == 0) ? 0.f : 1.f;    // m-col edge: j=0 of dj=-1
  const float e7 = (x8 == 88) ? 0.f : 1.f;   // m-col edge: j=7 of dj=+1
  float rnv[8];
  *(f32x4*)(rnv) = *(const f32x4*)(rnorm + m8);
  *(f32x4*)(rnv + 4) = *(const f32x4*)(rnorm + m8 + 4);
  const int ib = nbase * NPIX + m8 + (int)GUARD_ELEMS;

#pragma unroll 4
  for (int si = 0; si < 16; ++si) {
    const int s = sh * 16 + si;
    const int n = nbase + s;
    const int yn = n / WW;
    const int xn = n - yn * WW;
    const float cn0 = (xn >= 1) ? 1.f : 0.f;
    const float cn2 = (xn <= 94) ? 1.f : 0.f;
    float rbv[3];
    rbv[0] = (yn >= 1) ? rm0 : 0.f;
    rbv[1] = 1.f;
    rbv[2] = (yn <= 94) ? rm2 : 0.f;
    const int base = ib + s * NPIX;
    float d[8] = {0.f, 0.f, 0.f, 0.f, 0.f, 0.f, 0.f, 0.f};
#pragma unroll
    for (int t = 0; t < 3; ++t) {            // di = t-1
      const int rbase = base + (t - 1) * DROW;
      const float wc = rbv[t];
      const float wl = wc * cn0;
      const float wr = wc * cn2;
      // center tap (delta co-shift 0): aligned half8
      half8 C = *(const half8*)(Gg + rbase);
      // left tap (delta -1): elems rbase-9217+j ; j=0 scalar + aligned half8
      _Float16 P = Gg[rbase - DDIAG];
      half8 L = *(const half8*)(Gg + rbase - DDIAG + 1);
      // right tap (delta +1): elems rbase+9217+j ; aligned half8 + j=7 scalar
      half8 R = *(const half8*)(Gg + rbase + DDIAG - 1);
      _Float16 X = Gg[rbase + DDIAG + 7];
#pragma unroll
      for (int j = 0; j < 8; ++j) d[j] = fmaf((float)C[j], wc, d[j]);
      d[0] = fmaf((float)P, wl * e0, d[0]);
#pragma unroll
      for (int j = 1; j < 8; ++j) d[j] = fmaf((float)L[j - 1], wl, d[j]);
#pragma unroll
      for (int j = 0; j < 7; ++j) d[j] = fmaf((float)R[j + 1], wr, d[j]);
      d[7] = fmaf((float)X, wr * e7, d[7]);
    }
    // score + argmax (ascending m; strict > keeps first max)
    float bv = d[0] * rnv[0];
    int bj = m8;
#pragma unroll
    for (int j = 1; j < 8; ++j) {
      float xsc = d[j] * rnv[j];
      if (xsc > bv) { bv = xsc; bj = m8 + j; }
    }
#pragma unroll
    for (int mm = 1; mm < 64; mm <<= 1) {
      float ov = __shfl_xor(bv, mm, 64);
      int oi = __shfl_xor(bj, mm, 64);
      if (ov > bv || (ov == bv && oi < bj)) { bv = ov; bj = oi; }
    }
    if (lane == 0) {
      unsigned u = __float_as_uint(bv);
      u ^= (unsigned)((int)u >> 31) | 0x80000000u;
      unsigned long long key =
          ((unsigned long long)u << 32) | (unsigned)(0xFFFFFFFFu ^ (unsigned)bj);
      atomicMax(keytab + n, key);
    }
  }
}

// recon+MSE (new path): content from Ct f16, style from styT f32
__global__ __launch_bounds__(256)
void recon_mse2_kernel(const _Float16* __restrict__ Ct, const float* __restrict__ styT,
                       const unsigned long long* __restrict__ keytab, float* __restrict__ out) {
  const int pix = blockIdx.x * 2 + (threadIdx.x >> 7);
  const int c = threadIdx.x & 127;
  const int y = pix / WW, x = pix - (pix / WW) * WW;
  float sum = 0.f, cnt = 0.f;
#pragma unroll
  for (int ki = 0; ki < 3; ++ki) {
    int yn = y - ki + 1;
    if (yn < 0 || yn >= HH) continue;
#pragma unroll
    for (int kj = 0; kj < 3; ++kj) {
      int xn = x - kj + 1;
      if (xn < 0 || xn >= WW) continue;
      cnt += 1.f;
      int m = (int)(0xFFFFFFFFu ^ (unsigned)(keytab[yn * WW + xn] & 0xFFFFFFFFull));
      int ys = m / WW, xs = m - (m / WW) * WW;
      int sy = ys + ki - 1, sx = xs + kj - 1;
      if (sy >= 0 && sy < HH && sx >= 0 && sx < WW)
        sum += styT[(size_t)(sy * WW + sx) * NCH + c];
    }
  }
  float recon = sum / (cnt + 1e-8f);
  float cv = (float)Ct[(size_t)pix * NCH + c];
  float diff = cv - recon;
  float sq = diff * diff;
#pragma unroll
  for (int m = 32; m > 0; m >>= 1) sq += __shfl_down(sq, m, 64);
  __shared__ float wsum[4];
  int lane = threadIdx.x & 63, w = threadIdx.x >> 6;
  if (lane == 0) wsum[w] = sq;
  __syncthreads();
  if (threadIdx.x == 0)
    atomicAdd(out, (wsum[0] + wsum[1] + wsum[2] + wsum[3]) * (1.0f / (float)TOTAL_ELEMS));
}

// ======================= OLD PATH (round-3, fallback) =======================
__global__ __launch_bounds__(256)
void build_patches_old(const float* __restrict__ style_f, const float* __restrict__ content_f,
                       __bf16* __restrict__ Ps, __bf16* __restrict__ Pc) {
  __shared__ float ftile[CG][3][104];
  const int y = blockIdx.x;
  const int cg = blockIdx.y;
  const bool is_style = (blockIdx.z == 0);
  const float* f = is_style ? style_f : content_f;
  __bf16* P = is_style ? Ps : Pc;
  const int tid = threadIdx.x;
  for (int i = tid; i < CG * 3 * 96; i += 256) {
    int cl = i / 288, rem = i - cl * 288;
    int yy = rem / 96, xx = rem - yy * 96;
    int gy = y + yy - 1;
    float v = (gy >= 0 && gy < HH) ? f[(size_t)(cg * CG + cl) * NPIX + gy * WW + xx] : 0.f;
    ftile[cl][yy][xx] = v;
  }
  __syncthreads();
  for (int j = tid; j < 96 * 36; j += 256) {
    int px = j / 36, wi = j - px * 36;
    bf16x8 tmp;
#pragma unroll
    for (int u = 0; u < 8; ++u) {
      int e = wi * 8 + u;
      int cl = e / 9, t = e - cl * 9;
      int ki = t / 3, kj = t - ki * 3;
      int xx = px + kj - 1;
      float v = (xx >= 0 && xx < WW) ? ftile[cl][ki][xx] : 0.f;
      tmp[u] = (__bf16)v;
    }
    *(bf16x8*)(P + (size_t)(y * WW + px) * DDIM + cg * 288 + wi * 8) = tmp;
  }
}

__global__ __launch_bounds__(256)
void norm_old(const __bf16* __restrict__ Ps, float* __restrict__ rnorm) {
  const int n = blockIdx.x * 4 + (threadIdx.x >> 6);
  const int lane = threadIdx.x & 63;
  const bf16x8* row = (const bf16x8*)(Ps + (size_t)n * DDIM);
  float ss = 0.f;
#pragma unroll
  for (int i = 0; i < 3; ++i) {
    int idx = i * 64 + lane;
    if (idx < 144) {
      bf16x8 v = row[idx];
#pragma unroll
      for (int u = 0; u < 8; ++u) { float x = (float)v[u]; ss += x * x; }
    }
  }
#pragma unroll
  for (int m = 1; m < 64; m <<= 1) ss += __shfl_xor(ss, m, 64);
  if (lane == 0) rnorm[n] = 1.0f / fmaxf(sqrtf(ss), 1e-12f);
}

__global__ __launch_bounds__(256, 2)
void gemm_old(const __bf16* __restrict__ Pc, const __bf16* __restrict__ Ps,
              const float* __restrict__ rnorm, unsigned long long* __restrict__ keytab) {
  __shared__ int4 smem4[4608];
  char* smem = (char*)smem4;
  const int tid = threadIdx.x;
  const int lane = tid & 63;
  const int wid = tid >> 6;
  const int l15 = lane & 15;
  const int lg = lane >> 4;
  const int wm = wid >> 1;
  const int wn = wid & 1;
  const int orig = blockIdx.x;
  const int swz = (orig & 7) * 324 + (orig >> 3);
  const int mt = swz / 72;
  const int nt = swz - mt * 72;
  const int bm0 = mt * 256;
  const int sbase = nt * 128;
  const int srow = tid >> 2;
  const int sg = (tid & 3) ^ ((srow >> 1) & 3);
  const __bf16* pa = Pc + (size_t)(bm0 + srow) * DDIM + sg * 8;
  const __bf16* pb = Ps + (size_t)(sbase + srow) * DDIM + sg * 8;
  const int sdst = tid * 16;
  auto stage = [&](int buf, int kt) {
    char* la = smem + buf * 24576 + sdst;
    const int ko = kt * 32;
#pragma unroll
    for (int i = 0; i < 4; ++i) gload_lds16(pa + (size_t)i * 64 * DDIM + ko, la + i * 4096);
#pragma unroll
    for (int j = 0; j < 2; ++j) gload_lds16(pb + (size_t)j * 64 * DDIM + ko, la + 16384 + j * 4096);
  };
  const int sx = (lg ^ ((l15 >> 1) & 3)) << 4;
  int aoff[8], boff[4];
#pragma unroll
  for (int mf = 0; mf < 8; ++mf) aoff[mf] = (wm * 128 + mf * 16 + l15) * 64 + sx;
#pragma unroll
  for (int nf = 0; nf < 4; ++nf) boff[nf] = 16384 + (wn * 64 + nf * 16 + l15) * 64 + sx;
  f32x4 acc[8][4];
#pragma unroll
  for (int mf = 0; mf < 8; ++mf)
#pragma unroll
    for (int nf = 0; nf < 4; ++nf) {
      f32x4 z = {0.f, 0.f, 0.f, 0.f};
      acc[mf][nf] = z;
    }
  auto compute = [&](int buf) {
    const char* bp = smem + buf * 24576;
    bf16x8 af[8], bfr[4];
#pragma unroll
    for (int mf = 0; mf < 8; ++mf) af[mf] = __builtin_bit_cast(bf16x8, *(const int4*)(bp + aoff[mf]));
#pragma unroll
    for (int nf = 0; nf < 4; ++nf) bfr[nf] = __builtin_bit_cast(bf16x8, *(const int4*)(bp + boff[nf]));
    __builtin_amdgcn_s_setprio(1);
#pragma unroll
    for (int mf = 0; mf < 8; ++mf)
#pragma unroll
      for (int nf = 0; nf < 4; ++nf)
        acc[mf][nf] = __builtin_amdgcn_mfma_f32_16x16x32_bf16(af[mf], bfr[nf], acc[mf][nf], 0, 0, 0);
    __builtin_amdgcn_s_setprio(0);
  };
  stage(0, 0);
  stage(1, 1);
  int sb = 2, cb = 0;
  for (int kt = 0; kt < 34; ++kt) {
    stage(sb, kt + 2);
    sb = (sb == 2) ? 0 : sb + 1;
    asm volatile("s_waitcnt vmcnt(12)" ::: "memory");
    __builtin_amdgcn_s_barrier();
    __builtin_amdgcn_sched_barrier(0);
    compute(cb);
    __builtin_amdgcn_s_barrier();
    cb = (cb == 2) ? 0 : cb + 1;
  }
  asm volatile("s_waitcnt vmcnt(6)" ::: "memory");
  __builtin_amdgcn_s_barrier();
  __builtin_amdgcn_sched_barrier(0);
  compute(cb);
  cb = (cb == 2) ? 0 : cb + 1;
  asm volatile("s_waitcnt vmcnt(0)" ::: "memory");
  __builtin_amdgcn_s_barrier();
  __builtin_amdgcn_sched_barrier(0);
  compute(cb);
  float rn[4];
#pragma unroll
  for (int nf = 0; nf < 4; ++nf) rn[nf] = rnorm[sbase + wn * 64 + nf * 16 + l15];
#pragma unroll
  for (int mf = 0; mf < 8; ++mf)
#pragma unroll
    for (int r = 0; r < 4; ++r) {
      float v = -3.0e38f;
      int bi = 0;
#pragma unroll
      for (int nf = 0; nf < 4; ++nf) {
        float x = acc[mf][nf][r] * rn[nf];
        int col = sbase + wn * 64 + nf * 16 + l15;
        if (x > v) { v = x; bi = col; }
      }
#pragma unroll
      for (int m = 1; m < 16; m <<= 1) {
        float ov = __shfl_xor(v, m, 64);
        int oi = __shfl_xor(bi, m, 64);
        if (ov > v || (ov == v && oi < bi)) { v = ov; bi = oi; }
      }
      if (l15 == 0) {
        int row = bm0 + wm * 128 + mf * 16 + lg * 4 + r;
        unsigned u = __float_as_uint(v);
        u ^= (unsigned)((int)u >> 31) | 0x80000000u;
        unsigned long long key = ((unsigned long long)u << 32) | (unsigned)(0xFFFFFFFFu ^ (unsigned)bi);
        atomicMax(keytab + row, key);
      }
    }
}

__global__ __launch_bounds__(256)
void recon_old(const __bf16* __restrict__ Pc, const __bf16* __restrict__ Ps,
               const unsigned long long* __restrict__ keytab, float* __restrict__ out) {
  const int pix = blockIdx.x * 2 + (threadIdx.x >> 7);
  const int c = threadIdx.x & 127;
  const int y = pix / WW, x = pix - (pix / WW) * WW;
  float sum = 0.f, cnt = 0.f;
#pragma unroll
  for (int ki = 0; ki < 3; ++ki) {
    int yn = y - ki + 1;
    if (yn < 0 || yn >= HH) continue;
#pragma unroll
    for (int kj = 0; kj < 3; ++kj) {
      int xn = x - kj + 1;
      if (xn < 0 || xn >= WW) continue;
      cnt += 1.f;
      int m = (int)(0xFFFFFFFFu ^ (unsigned)(keytab[yn * WW + xn] & 0xFFFFFFFFull));
      sum += (float)Ps[(size_t)m * DDIM + c * 9 + ki * 3 + kj];
    }
  }
  float recon = sum / (cnt + 1e-8f);
  float cv = (float)Pc[(size_t)pix * DDIM + c * 9 + 4];
  float diff = cv - recon;
  float sq = diff * diff;
#pragma unroll
  for (int m = 32; m > 0; m >>= 1) sq += __shfl_down(sq, m, 64);
  __shared__ float wsum[4];
  int lane = threadIdx.x & 63, w = threadIdx.x >> 6;
  if (lane == 0) wsum[w] = sq;
  __syncthreads();
  if (threadIdx.x == 0)
    atomicAdd(out, (wsum[0] + wsum[1] + wsum[2] + wsum[3]) * (1.0f / (float)TOTAL_ELEMS));
}

extern "C" void kernel_launch(void* const* d_in, const int* in_sizes, int n_in,
                              void* d_out, int out_size, void* d_ws, size_t ws_size,
                              hipStream_t stream) {
  const float* content = (const float*)d_in[0];
  const float* stylef = (const float*)d_in[1];
  float* out = (float*)d_out;
  char* ws = (char*)d_ws;

  hipMemsetAsync(d_out, 0, (size_t)out_size * sizeof(float), stream);

  if (ws_size >= NEED_NEW) {
    _Float16* Gg = (_Float16*)ws;
    _Float16* Ct = (_Float16*)(ws + CT_OFF);
    _Float16* St = (_Float16*)(ws + ST2_OFF);
    float* styT = (float*)(ws + STYT_OFF);
    float* ss = (float*)(ws + SS_OFF);
    float* rnorm = (float*)(ws + RN2_OFF);
    unsigned long long* keytab = (unsigned long long*)(ws + KEY2_OFF);

    hipMemsetAsync(keytab, 0, (size_t)NPIX * 8, stream);
    // zero guard bands: masked (x0) taps must not read NaN-capable poison
    hipMemsetAsync(Gg, 0, (size_t)GUARD_ELEMS * 2, stream);
    hipMemsetAsync(Gg + GUARD_ELEMS + G_CORE_ELEMS, 0, (size_t)GUARD_ELEMS * 2, stream);
    transpose_kernel<<<dim3(96, 2), 256, 0, stream>>>(stylef, content, St, Ct, styT);
    norm2_kernel<<<NPIX / 4, 256, 0, stream>>>(styT, ss);
    boxnorm_kernel<<<NPIX / 256, 256, 0, stream>>>(ss, rnorm);
    ggemm_kernel<<<dim3(72, 72), 256, 0, stream>>>(Ct, St, (unsigned short*)Gg);
    dist_argmax_kernel<<<2592, 256, 0, stream>>>(Gg, rnorm, keytab);
    recon_mse2_kernel<<<NPIX / 2, 256, 0, stream>>>(Ct, styT, keytab, out);
  } else {
    const size_t PS_OFF = 0;
    const size_t PC_OFF = (size_t)NPIX * DDIM * 2;
    const size_t RN_OFF = PC_OFF * 2;
    const size_t KEY_OFF = RN_OFF + (size_t)NPIX * 4;
    __bf16* Ps = (__bf16*)(ws + PS_OFF);
    __bf16* Pc = (__bf16*)(ws + PC_OFF);
    float* rnorm = (float*)(ws + RN_OFF);
    unsigned long long* keytab = (unsigned long long*)(ws + KEY_OFF);
    hipMemsetAsync(keytab, 0, (size_t)NPIX * 8, stream);
    build_patches_old<<<dim3(96, 4, 2), 256, 0, stream>>>(stylef, content, Ps, Pc);
    norm_old<<<NPIX / 4, 256, 0, stream>>>(Ps, rnorm);
    gemm_old<<<2592, 256, 0, stream>>>(Pc, Ps, rnorm, keytab);
    recon_old<<<NPIX / 2, 256, 0, stream>>>(Pc, Ps, keytab, out);
  }
}

// Round 9
// 244.321 us; speedup vs baseline: 1.6821x; 1.0470x over previous
//
#include <hip/hip_runtime.h>
#include <hip/hip_bf16.h>

#define HH 96
#define WW 96
#define NPIX 9216
#define NCH 128
#define DDIM 1152
#define TOTAL_ELEMS 1179648
#define CG 32
#define DDIAG 9217            // NPIX+1 (diagonal flat step)
#define DROW 884832           // 96*9217

typedef float f32x4 __attribute__((ext_vector_type(4)));
typedef __bf16 bf16x8 __attribute__((ext_vector_type(8)));
typedef _Float16 half8 __attribute__((ext_vector_type(8)));

__device__ __forceinline__ void gload_lds16(const void* g, void* l) {
  __builtin_amdgcn_global_load_lds((const __attribute__((address_space(1))) void*)g,
                                   (__attribute__((address_space(3))) void*)l, 16, 0, 0);
}

// ======================= NEW PATH (G-factorized, f16) =======================
// G(a,b) = sum_c Ct[a,c]*St[b,c];  dist(n,m) = sum_{delta} G(n+delta, m+delta),
// delta = (di-1)*96 + (dj-1), masked; flat offset = delta*(NPIX+1).

#define GUARD_ELEMS 894064ull                   // >= 97*9217+8, multiple of 8
constexpr size_t G_CORE_ELEMS = (size_t)NPIX * NPIX;
constexpr size_t G_TOT_ELEMS = G_CORE_ELEMS + 2ull * GUARD_ELEMS;
constexpr size_t GBYTES = ((G_TOT_ELEMS * 2 + 255) & ~(size_t)255);
constexpr size_t CT_OFF = GBYTES;
constexpr size_t ST2_OFF = CT_OFF + (size_t)NPIX * NCH * 2;
constexpr size_t STYT_OFF = ST2_OFF + (size_t)NPIX * NCH * 2;
constexpr size_t SS_OFF = STYT_OFF + (size_t)NPIX * NCH * 4;
constexpr size_t RN2_OFF = SS_OFF + (size_t)NPIX * 4;
constexpr size_t KEY2_OFF = RN2_OFF + (size_t)NPIX * 4;
constexpr size_t NEED_NEW = KEY2_OFF + (size_t)NPIX * 8;

// features [c][pix] f32 -> [pix][c] f16 (+ styT f32 and per-pixel ss for style)
__global__ __launch_bounds__(256)
void transpose_kernel(const float* __restrict__ style_f, const float* __restrict__ content_f,
                      _Float16* __restrict__ St, _Float16* __restrict__ Ct,
                      float* __restrict__ styT, float* __restrict__ ss) {
  __shared__ float ftile[NCH][97];
  const int y = blockIdx.x;
  const bool is_style = (blockIdx.y == 0);
  const float* f = is_style ? style_f : content_f;
  _Float16* P = is_style ? St : Ct;
  const int tid = threadIdx.x;
  for (int i = tid; i < NCH * WW; i += 256) {
    int c = i / WW, x = i - (i / WW) * WW;
    ftile[c][x] = f[(size_t)c * NPIX + y * WW + x];
  }
  __syncthreads();
  for (int j = tid; j < WW * NCH; j += 256) {
    int x = j >> 7, c = j & 127;
    float v = ftile[c][x];
    P[(size_t)(y * WW + x) * NCH + c] = (_Float16)v;
    if (is_style) styT[(size_t)(y * WW + x) * NCH + c] = v;
  }
  if (is_style && tid < WW) {
    float s = 0.f;
#pragma unroll 8
    for (int c = 0; c < NCH; ++c) { float v = ftile[c][tid]; s = fmaf(v, v, s); }
    ss[y * WW + tid] = s;
  }
}

// patch norm: masked 3x3 box-sum of ss -> rnorm = 1/max(sqrt, 1e-12)
__global__ __launch_bounds__(256)
void boxnorm_kernel(const float* __restrict__ ss, float* __restrict__ rnorm) {
  int m = blockIdx.x * 256 + threadIdx.x;
  int ym = m / WW, xm = m - (m / WW) * WW;
  float s = 0.f;
#pragma unroll
  for (int di = -1; di <= 1; ++di) {
    int yy = ym + di;
    if (yy < 0 || yy >= HH) continue;
#pragma unroll
    for (int dj = -1; dj <= 1; ++dj) {
      int xx = xm + dj;
      if (xx < 0 || xx >= WW) continue;
      s += ss[yy * WW + xx];
    }
  }
  rnorm[m] = 1.0f / fmaxf(sqrtf(s), 1e-12f);
}

// G-GEMM: 128x128 tile, K=128 single shot, f16 MFMA. 4 waves (2Mx2N), wave 64x64.
__global__ __launch_bounds__(256, 2)
void ggemm_kernel(const _Float16* __restrict__ Ct, const _Float16* __restrict__ St,
                  unsigned short* __restrict__ Gg) {
  __shared__ char smem[65536];  // A 32KB + B 32KB; reused for f16 repack
  const int tid = threadIdx.x;
  const int lane = tid & 63, wid = tid >> 6;
  const int l15 = lane & 15, lg = lane >> 4;
  const int wm = wid >> 1, wn = wid & 1;
  const int n0 = blockIdx.x * 128, m0 = blockIdx.y * 128;

  {  // stage A,B with slot-XOR swizzle (phys slot = logical ^ (row&7))
    const int r = tid >> 4, p = tid & 15;
    const int l = p ^ (r & 7);
    const _Float16* sa = Ct + (size_t)(n0 + r) * NCH + l * 8;
    const _Float16* sb = St + (size_t)(m0 + r) * NCH + l * 8;
    char* d = smem + tid * 16;
#pragma unroll
    for (int i = 0; i < 8; ++i) {
      gload_lds16(sa + (size_t)16 * i * NCH, d + 4096 * i);
      gload_lds16(sb + (size_t)16 * i * NCH, d + 32768 + 4096 * i);
    }
  }
  __syncthreads();

  f32x4 acc[4][4];
#pragma unroll
  for (int mf = 0; mf < 4; ++mf)
#pragma unroll
    for (int nf = 0; nf < 4; ++nf) {
      f32x4 z = {0.f, 0.f, 0.f, 0.f};
      acc[mf][nf] = z;
    }

#pragma unroll
  for (int ks = 0; ks < 4; ++ks) {
    half8 af[4], bb[4];
#pragma unroll
    for (int mf = 0; mf < 4; ++mf) {
      int row = wm * 64 + mf * 16 + l15;
      int phys = (ks * 4 + lg) ^ (row & 7);
      af[mf] = __builtin_bit_cast(half8, *(const int4*)(smem + row * 256 + phys * 16));
    }
#pragma unroll
    for (int nf = 0; nf < 4; ++nf) {
      int row = wn * 64 + nf * 16 + l15;
      int phys = (ks * 4 + lg) ^ (row & 7);
      bb[nf] = __builtin_bit_cast(half8, *(const int4*)(smem + 32768 + row * 256 + phys * 16));
    }
#pragma unroll
    for (int mf = 0; mf < 4; ++mf)
#pragma unroll
      for (int nf = 0; nf < 4; ++nf)
        acc[mf][nf] = __builtin_amdgcn_mfma_f32_16x16x32_f16(af[mf], bb[nf], acc[mf][nf], 0, 0, 0);
  }
  __syncthreads();  // all LDS reads done before repack overwrite

  // repack acc -> f16 LDS [128][136], then coalesced dwordx4 stores
#pragma unroll
  for (int mf = 0; mf < 4; ++mf)
#pragma unroll
    for (int nf = 0; nf < 4; ++nf)
#pragma unroll
      for (int r = 0; r < 4; ++r) {
        int row = wm * 64 + mf * 16 + lg * 4 + r;
        int col = wn * 64 + nf * 16 + l15;
        *(_Float16*)(smem + (row * 136 + col) * 2) = (_Float16)acc[mf][nf][r];
      }
  __syncthreads();
  const size_t gbase = GUARD_ELEMS + (size_t)n0 * NPIX + m0;
#pragma unroll
  for (int j = 0; j < 8; ++j) {
    int idx = j * 256 + tid;
    int row = idx >> 4, ch = idx & 15;
    int4 v = *(const int4*)(smem + (row * 136 + ch * 8) * 2);
    *(int4*)(Gg + gbase + (size_t)row * NPIX + ch * 8) = v;
  }
}

// dist + argmax: 2592 blocks = 8 XCDs x 9 n-tiles x 18 m-splits x 2 s-halves.
// Wave owns 16 n; lane owns 8 consecutive m; 9 diagonal f16 taps via hoisted,
// per-s-stepped pointers; value-only wave max + predicated keyed atomic.
__global__ __launch_bounds__(256)
void dist_argmax_kernel(const _Float16* __restrict__ Gg, const float* __restrict__ rnorm,
                        unsigned long long* __restrict__ keytab) {
  const int bid = blockIdx.x;
  const int xcd = bid & 7;
  const int local = bid >> 3;                 // 0..323
  const int nt = xcd * 9 + (local % 9);       // 0..71
  const int rest = local / 9;                 // 0..35
  const int ms = rest % 18;                   // 0..17
  const int sh = rest / 18;                   // 0..1
  const int w = threadIdx.x >> 6;
  const int lane = threadIdx.x & 63;
  const int n0 = nt * 128 + w * 32 + sh * 16;
  const int m8 = ms * 512 + lane * 8;

  const int ym = m8 / WW;
  const int x8 = m8 - ym * WW;               // multiple of 8 -> no x-wrap in the 8
  const float me0 = (x8 == 0) ? 0.f : 1.f;   // m-col edge: j=0 of dj=-1
  const float me7 = (x8 == 88) ? 0.f : 1.f;  // m-col edge: j=7 of dj=+1
  const bool mr0 = (ym >= 1);
  const bool mr2 = (ym <= 94);
  float rnv[8];
  *(f32x4*)(rnv) = *(const f32x4*)(rnorm + m8);
  *(f32x4*)(rnv + 4) = *(const f32x4*)(rnorm + m8 + 4);

  // 9 tap pointers, hoisted; each stepped by +NPIX per s (uniform).
  const _Float16* base = Gg + ((size_t)n0 * NPIX + (size_t)m8 + GUARD_ELEMS);
  const _Float16* pL0 = base - DROW - DDIAG;     // scalar @0, half8 @1
  const _Float16* pC0 = base - DROW;             // half8 @0
  const _Float16* pR0 = base - DROW + DDIAG - 1; // half8 @0, scalar @8
  const _Float16* pL1 = base - DDIAG;
  const _Float16* pC1 = base;
  const _Float16* pR1 = base + DDIAG - 1;
  const _Float16* pL2 = base + DROW - DDIAG;
  const _Float16* pC2 = base + DROW;
  const _Float16* pR2 = base + DROW + DDIAG - 1;

  int yn = n0 / WW;
  int xn = n0 - yn * WW;

#pragma unroll 2
  for (int s = 0; s < 16; ++s) {
    const int n = n0 + s;
    const float cn0 = (xn >= 1) ? 1.f : 0.f;
    const float cn2 = (xn <= 94) ? 1.f : 0.f;
    const float rb0 = (mr0 && (yn >= 1)) ? 1.f : 0.f;
    const float rb2 = (mr2 && (yn <= 94)) ? 1.f : 0.f;
    float d[8];
    {  // t=1 (row weight 1): init d from center tap
      half8 C = *(const half8*)pC1;
      _Float16 P = pL1[0];
      half8 L = *(const half8*)(pL1 + 1);
      half8 R = *(const half8*)pR1;
      _Float16 X = pR1[8];
#pragma unroll
      for (int j = 0; j < 8; ++j) d[j] = (float)C[j];
      d[0] = fmaf((float)P, cn0 * me0, d[0]);
#pragma unroll
      for (int j = 1; j < 8; ++j) d[j] = fmaf((float)L[j - 1], cn0, d[j]);
#pragma unroll
      for (int j = 0; j < 7; ++j) d[j] = fmaf((float)R[j + 1], cn2, d[j]);
      d[7] = fmaf((float)X, cn2 * me7, d[7]);
    }
    {  // t=0 (row weight rb0)
      const float wl = rb0 * cn0, wr = rb0 * cn2;
      half8 C = *(const half8*)pC0;
      _Float16 P = pL0[0];
      half8 L = *(const half8*)(pL0 + 1);
      half8 R = *(const half8*)pR0;
      _Float16 X = pR0[8];
#pragma unroll
      for (int j = 0; j < 8; ++j) d[j] = fmaf((float)C[j], rb0, d[j]);
      d[0] = fmaf((float)P, wl * me0, d[0]);
#pragma unroll
      for (int j = 1; j < 8; ++j) d[j] = fmaf((float)L[j - 1], wl, d[j]);
#pragma unroll
      for (int j = 0; j < 7; ++j) d[j] = fmaf((float)R[j + 1], wr, d[j]);
      d[7] = fmaf((float)X, wr * me7, d[7]);
    }
    {  // t=2 (row weight rb2)
      const float wl = rb2 * cn0, wr = rb2 * cn2;
      half8 C = *(const half8*)pC2;
      _Float16 P = pL2[0];
      half8 L = *(const half8*)(pL2 + 1);
      half8 R = *(const half8*)pR2;
      _Float16 X = pR2[8];
#pragma unroll
      for (int j = 0; j < 8; ++j) d[j] = fmaf((float)C[j], rb2, d[j]);
      d[0] = fmaf((float)P, wl * me0, d[0]);
#pragma unroll
      for (int j = 1; j < 8; ++j) d[j] = fmaf((float)L[j - 1], wl, d[j]);
#pragma unroll
      for (int j = 0; j < 7; ++j) d[j] = fmaf((float)R[j + 1], wr, d[j]);
      d[7] = fmaf((float)X, wr * me7, d[7]);
    }
    // per-lane argmax (ascending m; strict > keeps first max)
    float bv = d[0] * rnv[0];
    int bj = m8;
#pragma unroll
    for (int j = 1; j < 8; ++j) {
      float xs = d[j] * rnv[j];
      if (xs > bv) { bv = xs; bj = m8 + j; }
    }
    // value-only wave max; tie lanes all publish, 64-bit key resolves min-index
    float wmx = bv;
#pragma unroll
    for (int mm = 1; mm < 64; mm <<= 1)
      wmx = fmaxf(wmx, __shfl_xor(wmx, mm, 64));
    if (bv == wmx) {
      unsigned u = __float_as_uint(bv);
      u ^= (unsigned)((int)u >> 31) | 0x80000000u;
      unsigned long long key =
          ((unsigned long long)u << 32) | (unsigned)(0xFFFFFFFFu ^ (unsigned)bj);
      atomicMax(keytab + n, key);
    }
    // advance
    pL0 += NPIX; pC0 += NPIX; pR0 += NPIX;
    pL1 += NPIX; pC1 += NPIX; pR1 += NPIX;
    pL2 += NPIX; pC2 += NPIX; pR2 += NPIX;
    ++xn;
    if (xn == WW) { xn = 0; ++yn; }
  }
}

// recon+MSE (new path): content from Ct f16, style from styT f32
__global__ __launch_bounds__(256)
void recon_mse2_kernel(const _Float16* __restrict__ Ct, const float* __restrict__ styT,
                       const unsigned long long* __restrict__ keytab, float* __restrict__ out) {
  const int pix = blockIdx.x * 2 + (threadIdx.x >> 7);
  const int c = threadIdx.x & 127;
  const int y = pix / WW, x = pix - (pix / WW) * WW;
  float sum = 0.f, cnt = 0.f;
#pragma unroll
  for (int ki = 0; ki < 3; ++ki) {
    int yn = y - ki + 1;
    if (yn < 0 || yn >= HH) continue;
#pragma unroll
    for (int kj = 0; kj < 3; ++kj) {
      int xn = x - kj + 1;
      if (xn < 0 || xn >= WW) continue;
      cnt += 1.f;
      int m = (int)(0xFFFFFFFFu ^ (unsigned)(keytab[yn * WW + xn] & 0xFFFFFFFFull));
      int ys = m / WW, xs = m - (m / WW) * WW;
      int sy = ys + ki - 1, sx = xs + kj - 1;
      if (sy >= 0 && sy < HH && sx >= 0 && sx < WW)
        sum += styT[(size_t)(sy * WW + sx) * NCH + c];
    }
  }
  float recon = sum / (cnt + 1e-8f);
  float cv = (float)Ct[(size_t)pix * NCH + c];
  float diff = cv - recon;
  float sq = diff * diff;
#pragma unroll
  for (int m = 32; m > 0; m >>= 1) sq += __shfl_down(sq, m, 64);
  __shared__ float wsum[4];
  int lane = threadIdx.x & 63, w = threadIdx.x >> 6;
  if (lane == 0) wsum[w] = sq;
  __syncthreads();
  if (threadIdx.x == 0)
    atomicAdd(out, (wsum[0] + wsum[1] + wsum[2] + wsum[3]) * (1.0f / (float)TOTAL_ELEMS));
}

// ======================= OLD PATH (round-3, fallback) =======================
__global__ __launch_bounds__(256)
void build_patches_old(const float* __restrict__ style_f, const float* __restrict__ content_f,
                       __bf16* __restrict__ Ps, __bf16* __restrict__ Pc) {
  __shared__ float ftile[CG][3][104];
  const int y = blockIdx.x;
  const int cg = blockIdx.y;
  const bool is_style = (blockIdx.z == 0);
  const float* f = is_style ? style_f : content_f;
  __bf16* P = is_style ? Ps : Pc;
  const int tid = threadIdx.x;
  for (int i = tid; i < CG * 3 * 96; i += 256) {
    int cl = i / 288, rem = i - cl * 288;
    int yy = rem / 96, xx = rem - yy * 96;
    int gy = y + yy - 1;
    float v = (gy >= 0 && gy < HH) ? f[(size_t)(cg * CG + cl) * NPIX + gy * WW + xx] : 0.f;
    ftile[cl][yy][xx] = v;
  }
  __syncthreads();
  for (int j = tid; j < 96 * 36; j += 256) {
    int px = j / 36, wi = j - px * 36;
    bf16x8 tmp;
#pragma unroll
    for (int u = 0; u < 8; ++u) {
      int e = wi * 8 + u;
      int cl = e / 9, t = e - cl * 9;
      int ki = t / 3, kj = t - ki * 3;
      int xx = px + kj - 1;
      float v = (xx >= 0 && xx < WW) ? ftile[cl][ki][xx] : 0.f;
      tmp[u] = (__bf16)v;
    }
    *(bf16x8*)(P + (size_t)(y * WW + px) * DDIM + cg * 288 + wi * 8) = tmp;
  }
}

__global__ __launch_bounds__(256)
void norm_old(const __bf16* __restrict__ Ps, float* __restrict__ rnorm) {
  const int n = blockIdx.x * 4 + (threadIdx.x >> 6);
  const int lane = threadIdx.x & 63;
  const bf16x8* row = (const bf16x8*)(Ps + (size_t)n * DDIM);
  float ss = 0.f;
#pragma unroll
  for (int i = 0; i < 3; ++i) {
    int idx = i * 64 + lane;
    if (idx < 144) {
      bf16x8 v = row[idx];
#pragma unroll
      for (int u = 0; u < 8; ++u) { float x = (float)v[u]; ss += x * x; }
    }
  }
#pragma unroll
  for (int m = 1; m < 64; m <<= 1) ss += __shfl_xor(ss, m, 64);
  if (lane == 0) rnorm[n] = 1.0f / fmaxf(sqrtf(ss), 1e-12f);
}

__global__ __launch_bounds__(256, 2)
void gemm_old(const __bf16* __restrict__ Pc, const __bf16* __restrict__ Ps,
              const float* __restrict__ rnorm, unsigned long long* __restrict__ keytab) {
  __shared__ int4 smem4[4608];
  char* smem = (char*)smem4;
  const int tid = threadIdx.x;
  const int lane = tid & 63;
  const int wid = tid >> 6;
  const int l15 = lane & 15;
  const int lg = lane >> 4;
  const int wm = wid >> 1;
  const int wn = wid & 1;
  const int orig = blockIdx.x;
  const int swz = (orig & 7) * 324 + (orig >> 3);
  const int mt = swz / 72;
  const int nt = swz - mt * 72;
  const int bm0 = mt * 256;
  const int sbase = nt * 128;
  const int srow = tid >> 2;
  const int sg = (tid & 3) ^ ((srow >> 1) & 3);
  const __bf16* pa = Pc + (size_t)(bm0 + srow) * DDIM + sg * 8;
  const __bf16* pb = Ps + (size_t)(sbase + srow) * DDIM + sg * 8;
  const int sdst = tid * 16;
  auto stage = [&](int buf, int kt) {
    char* la = smem + buf * 24576 + sdst;
    const int ko = kt * 32;
#pragma unroll
    for (int i = 0; i < 4; ++i) gload_lds16(pa + (size_t)i * 64 * DDIM + ko, la + i * 4096);
#pragma unroll
    for (int j = 0; j < 2; ++j) gload_lds16(pb + (size_t)j * 64 * DDIM + ko, la + 16384 + j * 4096);
  };
  const int sx = (lg ^ ((l15 >> 1) & 3)) << 4;
  int aoff[8], boff[4];
#pragma unroll
  for (int mf = 0; mf < 8; ++mf) aoff[mf] = (wm * 128 + mf * 16 + l15) * 64 + sx;
#pragma unroll
  for (int nf = 0; nf < 4; ++nf) boff[nf] = 16384 + (wn * 64 + nf * 16 + l15) * 64 + sx;
  f32x4 acc[8][4];
#pragma unroll
  for (int mf = 0; mf < 8; ++mf)
#pragma unroll
    for (int nf = 0; nf < 4; ++nf) {
      f32x4 z = {0.f, 0.f, 0.f, 0.f};
      acc[mf][nf] = z;
    }
  auto compute = [&](int buf) {
    const char* bp = smem + buf * 24576;
    bf16x8 af[8], bfr[4];
#pragma unroll
    for (int mf = 0; mf < 8; ++mf) af[mf] = __builtin_bit_cast(bf16x8, *(const int4*)(bp + aoff[mf]));
#pragma unroll
    for (int nf = 0; nf < 4; ++nf) bfr[nf] = __builtin_bit_cast(bf16x8, *(const int4*)(bp + boff[nf]));
    __builtin_amdgcn_s_setprio(1);
#pragma unroll
    for (int mf = 0; mf < 8; ++mf)
#pragma unroll
      for (int nf = 0; nf < 4; ++nf)
        acc[mf][nf] = __builtin_amdgcn_mfma_f32_16x16x32_bf16(af[mf], bfr[nf], acc[mf][nf], 0, 0, 0);
    __builtin_amdgcn_s_setprio(0);
  };
  stage(0, 0);
  stage(1, 1);
  int sb = 2, cb = 0;
  for (int kt = 0; kt < 34; ++kt) {
    stage(sb, kt + 2);
    sb = (sb == 2) ? 0 : sb + 1;
    asm volatile("s_waitcnt vmcnt(12)" ::: "memory");
    __builtin_amdgcn_s_barrier();
    __builtin_amdgcn_sched_barrier(0);
    compute(cb);
    __builtin_amdgcn_s_barrier();
    cb = (cb == 2) ? 0 : cb + 1;
  }
  asm volatile("s_waitcnt vmcnt(6)" ::: "memory");
  __builtin_amdgcn_s_barrier();
  __builtin_amdgcn_sched_barrier(0);
  compute(cb);
  cb = (cb == 2) ? 0 : cb + 1;
  asm volatile("s_waitcnt vmcnt(0)" ::: "memory");
  __builtin_amdgcn_s_barrier();
  __builtin_amdgcn_sched_barrier(0);
  compute(cb);
  float rn[4];
#pragma unroll
  for (int nf = 0; nf < 4; ++nf) rn[nf] = rnorm[sbase + wn * 64 + nf * 16 + l15];
#pragma unroll
  for (int mf = 0; mf < 8; ++mf)
#pragma unroll
    for (int r = 0; r < 4; ++r) {
      float v = -3.0e38f;
      int bi = 0;
#pragma unroll
      for (int nf = 0; nf < 4; ++nf) {
        float x = acc[mf][nf][r] * rn[nf];
        int col = sbase + wn * 64 + nf * 16 + l15;
        if (x > v) { v = x; bi = col; }
      }
#pragma unroll
      for (int m = 1; m < 16; m <<= 1) {
        float ov = __shfl_xor(v, m, 64);
        int oi = __shfl_xor(bi, m, 64);
        if (ov > v || (ov == v && oi < bi)) { v = ov; bi = oi; }
      }
      if (l15 == 0) {
        int row = bm0 + wm * 128 + mf * 16 + lg * 4 + r;
        unsigned u = __float_as_uint(v);
        u ^= (unsigned)((int)u >> 31) | 0x80000000u;
        unsigned long long key = ((unsigned long long)u << 32) | (unsigned)(0xFFFFFFFFu ^ (unsigned)bi);
        atomicMax(keytab + row, key);
      }
    }
}

__global__ __launch_bounds__(256)
void recon_old(const __bf16* __restrict__ Pc, const __bf16* __restrict__ Ps,
               const unsigned long long* __restrict__ keytab, float* __restrict__ out) {
  const int pix = blockIdx.x * 2 + (threadIdx.x >> 7);
  const int c = threadIdx.x & 127;
  const int y = pix / WW, x = pix - (pix / WW) * WW;
  float sum = 0.f, cnt = 0.f;
#pragma unroll
  for (int ki = 0; ki < 3; ++ki) {
    int yn = y - ki + 1;
    if (yn < 0 || yn >= HH) continue;
#pragma unroll
    for (int kj = 0; kj < 3; ++kj) {
      int xn = x - kj + 1;
      if (xn < 0 || xn >= WW) continue;
      cnt += 1.f;
      int m = (int)(0xFFFFFFFFu ^ (unsigned)(keytab[yn * WW + xn] & 0xFFFFFFFFull));
      sum += (float)Ps[(size_t)m * DDIM + c * 9 + ki * 3 + kj];
    }
  }
  float recon = sum / (cnt + 1e-8f);
  float cv = (float)Pc[(size_t)pix * DDIM + c * 9 + 4];
  float diff = cv - recon;
  float sq = diff * diff;
#pragma unroll
  for (int m = 32; m > 0; m >>= 1) sq += __shfl_down(sq, m, 64);
  __shared__ float wsum[4];
  int lane = threadIdx.x & 63, w = threadIdx.x >> 6;
  if (lane == 0) wsum[w] = sq;
  __syncthreads();
  if (threadIdx.x == 0)
    atomicAdd(out, (wsum[0] + wsum[1] + wsum[2] + wsum[3]) * (1.0f / (float)TOTAL_ELEMS));
}

extern "C" void kernel_launch(void* const* d_in, const int* in_sizes, int n_in,
                              void* d_out, int out_size, void* d_ws, size_t ws_size,
                              hipStream_t stream) {
  const float* content = (const float*)d_in[0];
  const float* stylef = (const float*)d_in[1];
  float* out = (float*)d_out;
  char* ws = (char*)d_ws;

  hipMemsetAsync(d_out, 0, (size_t)out_size * sizeof(float), stream);

  if (ws_size >= NEED_NEW) {
    _Float16* Gg = (_Float16*)ws;
    _Float16* Ct = (_Float16*)(ws + CT_OFF);
    _Float16* St = (_Float16*)(ws + ST2_OFF);
    float* styT = (float*)(ws + STYT_OFF);
    float* ss = (float*)(ws + SS_OFF);
    float* rnorm = (float*)(ws + RN2_OFF);
    unsigned long long* keytab = (unsigned long long*)(ws + KEY2_OFF);

    hipMemsetAsync(keytab, 0, (size_t)NPIX * 8, stream);
    // zero guard bands: masked (x0) taps must not read NaN-capable poison
    hipMemsetAsync(Gg, 0, (size_t)GUARD_ELEMS * 2, stream);
    hipMemsetAsync(Gg + GUARD_ELEMS + G_CORE_ELEMS, 0, (size_t)GUARD_ELEMS * 2, stream);
    transpose_kernel<<<dim3(96, 2), 256, 0, stream>>>(stylef, content, St, Ct, styT, ss);
    boxnorm_kernel<<<NPIX / 256, 256, 0, stream>>>(ss, rnorm);
    ggemm_kernel<<<dim3(72, 72), 256, 0, stream>>>(Ct, St, (unsigned short*)Gg);
    dist_argmax_kernel<<<2592, 256, 0, stream>>>(Gg, rnorm, keytab);
    recon_mse2_kernel<<<NPIX / 2, 256, 0, stream>>>(Ct, styT, keytab, out);
  } else {
    const size_t PS_OFF = 0;
    const size_t PC_OFF = (size_t)NPIX * DDIM * 2;
    const size_t RN_OFF = PC_OFF * 2;
    const size_t KEY_OFF = RN_OFF + (size_t)NPIX * 4;
    __bf16* Ps = (__bf16*)(ws + PS_OFF);
    __bf16* Pc = (__bf16*)(ws + PC_OFF);
    float* rnorm = (float*)(ws + RN_OFF);
    unsigned long long* keytab = (unsigned long long*)(ws + KEY_OFF);
    hipMemsetAsync(keytab, 0, (size_t)NPIX * 8, stream);
    build_patches_old<<<dim3(96, 4, 2), 256, 0, stream>>>(stylef, content, Ps, Pc);
    norm_old<<<NPIX / 4, 256, 0, stream>>>(Ps, rnorm);
    gemm_old<<<2592, 256, 0, stream>>>(Pc, Ps, rnorm, keytab);
    recon_old<<<NPIX / 2, 256, 0, stream>>>(Pc, Ps, keytab, out);
  }
}